// Round 12
// baseline (5402.389 us; speedup 1.0000x reference)
//
#include <hip/hip_runtime.h>
#include <hip/hip_bf16.h>

typedef unsigned short u16;
typedef unsigned int   u32;
typedef unsigned long long u64;
typedef __attribute__((ext_vector_type(8))) short short8;   // 8 x bf16 (4 VGPRs)
typedef __attribute__((ext_vector_type(4))) float f32x4;

#define DEVINL static __device__ __forceinline__

// round-to-nearest-even f32 -> bf16
DEVINL u16 f2bf(float x) {
  u32 u = __float_as_uint(x);
  u32 r = (u + 0x7fffu + ((u >> 16) & 1u)) >> 16;
  return (u16)r;
}

// async global->LDS, 16B per lane. LDS dest = uniform base + lane*16.
#define GLD16(gp, lp) __builtin_amdgcn_global_load_lds(                     \
    (const __attribute__((address_space(1))) u32*)(gp),                     \
    (__attribute__((address_space(3))) u32*)(lp), 16, 0, 0)

// ---------------------------------------------------------------------------
// fp32 -> bf16 bulk convert, ALL five weight tensors in one launch.
__global__ __launch_bounds__(256) void conv_all(
    const float* __restrict__ s0, u16* __restrict__ d0,
    const float* __restrict__ s1, u16* __restrict__ d1,
    const float* __restrict__ s2, u16* __restrict__ d2,
    const float* __restrict__ s3, u16* __restrict__ d3,
    const float* __restrict__ s4, u16* __restrict__ d4) {
  const float* s; u16* d; int local;
  int blk = blockIdx.x;
  if (blk < 16384) {
    int p = blk >> 12; local = blk & 4095;
    s = (p == 0) ? s0 : (p == 1) ? s1 : (p == 2) ? s2 : s3;
    d = (p == 0) ? d0 : (p == 1) ? d1 : (p == 2) ? d2 : d3;
  } else {
    s = s4; d = d4; local = blk - 16384;
  }
  int i = local * 256 + threadIdx.x;
  float4 v = ((const float4*)s)[i];
  ushort4 o;
  o.x = f2bf(v.x); o.y = f2bf(v.y); o.z = f2bf(v.z); o.w = f2bf(v.w);
  ((ushort4*)d)[i] = o;
}

// cond_e gather + fused bias vectors (bih+bhh) + zero barrier words
__global__ __launch_bounds__(256) void prep_small(
    const int* __restrict__ cond, const float* __restrict__ emb_cond,
    const float* __restrict__ bihN, const float* __restrict__ bhhN,
    const float* __restrict__ bihD, const float* __restrict__ bhhD,
    float* __restrict__ ce, float* __restrict__ biasN, float* __restrict__ biasD,
    u32* __restrict__ bar) {
  int tid = blockIdx.x * 256 + threadIdx.x;
  if (tid < 512) {
    int b = tid >> 3, j = tid & 7;
    ce[tid] = emb_cond[cond[b] * 8 + j];
  }
  if (tid < 128) bar[tid] = 0;
  int i = tid - 512;
  if (i >= 0 && i < 4096) {
    biasN[i] = bihN[i] + bhhN[i];
    biasD[i] = bihD[i] + bhhD[i];
  }
}

// encoder h0 = [zeros(B,1016), cond_e] -> bf16 into hbuf[0]
__global__ __launch_bounds__(256) void init_enc(const float* __restrict__ ce,
                                                u16* __restrict__ hb0) {
  int tid = blockIdx.x * 256 + threadIdx.x;   // 64*1024
  int b = tid >> 10, col = tid & 1023;
  float v = (col >= 1016) ? ce[b * 8 + (col - 1016)] : 0.f;
  hb0[tid] = f2bf(v);
}

// embedding row gather -> bf16, X[t*64+b][1024]
__global__ __launch_bounds__(256) void gather_kernel(const float* __restrict__ emb,
                                                     const int* __restrict__ words,
                                                     u16* __restrict__ X, int dec) {
  int r = blockIdx.x;                    // r = t*64 + b
  int t = r >> 6, b = r & 63;
  int tok = dec ? ((t == 0) ? 0 : words[b * 64 + t - 1]) : words[b * 64 + t];
  float4 v = ((const float4*)(emb + (size_t)tok * 1024))[threadIdx.x];
  ushort4 o;
  o.x = f2bf(v.x); o.y = f2bf(v.y); o.z = f2bf(v.z); o.w = f2bf(v.w);
  ((ushort4*)(X + (size_t)r * 1024))[threadIdx.x] = o;
}

// ---------------------------------------------------------------------------
// C = A(MxK) * B(NxK)^T + bias, bf16 in, fp32 out. 256x128 tile, BK=32,
// 512 threads = 8 waves (4m x 2n). MODE 0: n-fast + XCD swizzle (Xp GEMMs).
// MODE 1 (logits): per-XCD n-partition, NT stores. (Identical to round 11.)
template <int MODE>
__global__ __launch_bounds__(512) void gemm_bt_kernel(
    const u16* __restrict__ A, const u16* __restrict__ B,
    float* __restrict__ C, const float* __restrict__ bias, int N, int K) {
  __shared__ u16 lA[256 * 32];   // 16KB
  __shared__ u16 lB[128 * 32];   // 8KB
  const int tid = threadIdx.x;
  const int lane = tid & 63;
  const int wid = tid >> 6;      // 0..7

  int tile_m, tile_n;
  if (MODE == 0) {
    const int nn = N >> 7;
    const int nwg = gridDim.x;
    const int orig = blockIdx.x;
    const int wgid = (orig & 7) * (nwg >> 3) + (orig >> 3);
    tile_m = (wgid / nn) * 256;
    tile_n = (wgid % nn) * 128;
  } else {
    const int i = blockIdx.x;        // 0..4095
    const int x = i & 7;             // XCD id
    const int k = i >> 3;
    const int mg = k >> 6;
    const int r  = k & 63;
    const int kn = r >> 1;
    const int mi = r & 1;
    const int tn = kn * 8 + x;
    if (tn >= 250) return;
    tile_m = (mg * 2 + mi) * 256;
    tile_n = tn * 128;
  }
  const int wm = wid >> 1, wn = wid & 1;

  const int ldr = lane >> 2;
  const int lko = (lane & 3) * 8;
  const int l15 = lane & 15;
  const int g4 = lane >> 4;

  f32x4 acc[4][4];
#pragma unroll
  for (int i = 0; i < 4; ++i)
#pragma unroll
    for (int j = 0; j < 4; ++j) acc[i][j] = (f32x4)0.f;

  const size_t aBase = (size_t)tile_m * K;
  const size_t bBase = (size_t)tile_n * K;

  for (int k0 = 0; k0 < K; k0 += 32) {
    __syncthreads();
#pragma unroll
    for (int q = 0; q < 2; ++q) {
      int ch = wid * 2 + q;
      int row = ch * 16 + ldr;
      GLD16(A + aBase + (size_t)row * K + k0 + lko, &lA[ch * 512]);
    }
    {
      int row = wid * 16 + ldr;
      GLD16(B + bBase + (size_t)row * K + k0 + lko, &lB[wid * 512]);
    }
    __syncthreads();
    short8 af[4], bf[4];
#pragma unroll
    for (int i = 0; i < 4; ++i)
      af[i] = *(const short8*)&lA[(wm * 64 + i * 16 + l15) * 32 + g4 * 8];
#pragma unroll
    for (int j = 0; j < 4; ++j)
      bf[j] = *(const short8*)&lB[(wn * 64 + j * 16 + l15) * 32 + g4 * 8];
#pragma unroll
    for (int i = 0; i < 4; ++i)
#pragma unroll
      for (int j = 0; j < 4; ++j)
        acc[i][j] = __builtin_amdgcn_mfma_f32_16x16x32_bf16(af[i], bf[j], acc[i][j], 0, 0, 0);
  }

#pragma unroll
  for (int i = 0; i < 4; ++i) {
    int row0 = tile_m + wm * 64 + i * 16 + (g4 << 2);
#pragma unroll
    for (int j = 0; j < 4; ++j) {
      int col = tile_n + wn * 64 + j * 16 + l15;
      float bv = bias[col];
#pragma unroll
      for (int e = 0; e < 4; ++e) {
        size_t o = (size_t)(row0 + e) * (size_t)N + col;
        float v = acc[i][j][e] + bv;
        if (MODE == 1) __builtin_nontemporal_store(v, &C[o]);
        else           C[o] = v;
      }
    }
  }
}

// ---------------------------------------------------------------------------
// PERSISTENT LSTM, 64 steps, software grid barrier. 128 WGs x 512 threads,
// 80KB LDS -> >=2 WGs/CU residency capacity on 256 CUs: co-residency has
// 2x slack (r3/r4's 256WG/128KB zero-slack design is the suspected deadlock).
// WG (cg, half): gate-cols [cg*16,+16), batches [half*32,+32). Wave v:
// gate=v>>1, K-half=v&1. Whh fragments in VGPRs for ALL 64 steps (no
// per-step weight traffic). Cell state in registers. Cross-WG h traffic via
// agent-scope atomics (m20-verified): packed u32 stores, u64 loads ->
// XOR-swizzled ds_write. Barrier: seq-cst counter+flag, s_sleep spin.
__global__ __launch_bounds__(512, 1) void lstm_persist(
    const u16* __restrict__ Whh, const float* __restrict__ Xp,
    u16* __restrict__ hbuf,        // [2][64][1024] bf16 double buffer
    u16* __restrict__ hs_out,      // decoder: [b*64+t][1024] bf16, else null
    float* __restrict__ hT_out,    // encoder: [64][1024] fp32, else null
    u32* bar_cnt, u32* bar_flag) {
  __shared__ __align__(16) char smemA[65536];   // 32 rows x 2048B, swizzled
  __shared__ float lg[8][2][16][16];            // [wave][mtile][mrow][col]
  const int tid = threadIdx.x;      // 0..511
  const int lane = tid & 63;
  const int v = tid >> 6;           // wave 0..7
  const int gate = v >> 1;
  const int kh = v & 1;
  const int wgi = blockIdx.x;       // 0..127
  const int cg = wgi >> 1;          // col-group 0..63
  const int half = wgi & 1;         // batch half
  const int hc0 = cg * 16;
  const int b0 = half * 32;
  const int l15 = lane & 15;
  const int g4 = lane >> 4;

  // Whh fragments: loaded ONCE, live across all 64 steps (64 VGPRs)
  short8 breg[16];
  {
    const u16* Brow = Whh + (size_t)(gate * 1024 + hc0 + l15) * 1024
                          + kh * 512 + g4 * 8;
#pragma unroll
    for (int kk = 0; kk < 16; ++kk)
      breg[kk] = *(const short8*)(Brow + kk * 32);
  }

  // cell mapping: thread -> (bb = tid>>4 in 0..31, n = tid&15)
  const int bb = tid >> 4, n = tid & 15;
  const int b = b0 + bb, col = hc0 + n;
  float creg = 0.f;

  for (int t = 0; t < 64; ++t) {
    const u16* rb = hbuf + (size_t)(t & 1) * 65536;
    u32* wb32 = (u32*)(hbuf + (size_t)((t + 1) & 1) * 65536);

    // ---- stage h rows [b0, b0+32) -> swizzled LDS (64KB), atomic loads
#pragma unroll
    for (int q = 0; q < 8; ++q) {
      int g = q * 512 + tid;              // 16B chunk id 0..4095
      int row = g >> 7;                   // 0..31
      int cb = (g & 127) * 16;            // byte col in row
      const u64* src = (const u64*)((const char*)rb + (size_t)(b0 + row) * 2048 + cb);
      u64 lo = __hip_atomic_load(src,     __ATOMIC_RELAXED, __HIP_MEMORY_SCOPE_AGENT);
      u64 hi = __hip_atomic_load(src + 1, __ATOMIC_RELAXED, __HIP_MEMORY_SCOPE_AGENT);
      u64* d = (u64*)(smemA + row * 2048 + (cb ^ ((row & 7) << 4)));
      d[0] = lo; d[1] = hi;
    }
    // ---- Xp prefetch for this thread's cell
    size_t xrow = (size_t)(t * 64 + b) * 4096 + col;
    float xg0 = __builtin_nontemporal_load(&Xp[xrow]);
    float xg1 = __builtin_nontemporal_load(&Xp[xrow + 1024]);
    float xg2 = __builtin_nontemporal_load(&Xp[xrow + 2048]);
    float xg3 = __builtin_nontemporal_load(&Xp[xrow + 3072]);
    __syncthreads();

    // ---- 32 MFMAs/wave: 2 m-tiles x 16 k-steps of this wave's K-half
    f32x4 acc0 = (f32x4)0.f, acc1 = (f32x4)0.f;
#pragma unroll
    for (int kk = 0; kk < 16; ++kk) {
      int ct = (kh * 16 + kk) * 64 + g4 * 16;
      int sw = ct ^ ((l15 & 7) << 4);     // rows 16+l15 share (row&7)==(l15&7)
      const short8 a0 = *(const short8*)(smemA + l15 * 2048 + sw);
      const short8 a1 = *(const short8*)(smemA + (16 + l15) * 2048 + sw);
      acc0 = __builtin_amdgcn_mfma_f32_16x16x32_bf16(a0, breg[kk], acc0, 0, 0, 0);
      acc1 = __builtin_amdgcn_mfma_f32_16x16x32_bf16(a1, breg[kk], acc1, 0, 0, 0);
    }
    {
      int m0 = g4 * 4;
#pragma unroll
      for (int e = 0; e < 4; ++e) {
        lg[v][0][m0 + e][l15] = acc0[e];
        lg[v][1][m0 + e][l15] = acc1[e];
      }
    }
    __syncthreads();

    // ---- cell update: 1 cell per thread
    {
      int m = bb >> 4, r = bb & 15;
      float gi = lg[0][m][r][n] + lg[1][m][r][n] + xg0;
      float gf = lg[2][m][r][n] + lg[3][m][r][n] + xg1;
      float gg = lg[4][m][r][n] + lg[5][m][r][n] + xg2;
      float go = lg[6][m][r][n] + lg[7][m][r][n] + xg3;
      float si = 1.f / (1.f + __expf(-gi));
      float sf = 1.f / (1.f + __expf(-gf));
      float so = 1.f / (1.f + __expf(-go));
      float tg = tanhf(gg);
      float cn = sf * creg + si * tg;
      float hn = so * tanhf(cn);
      creg = cn;
      u16 h16 = f2bf(hn);
      // pack adjacent-n pair via shfl (partner lane = lane^1)
      u32 mine = h16;
      u32 other = (u32)__shfl_xor((int)mine, 1);
      if (!(n & 1)) {
        u32 pk = mine | (other << 16);
        size_t wi = ((size_t)b * 1024 + col) >> 1;
        __hip_atomic_store(wb32 + wi, pk, __ATOMIC_RELAXED,
                           __HIP_MEMORY_SCOPE_AGENT);
      }
      if (hs_out) hs_out[((size_t)b * 64 + t) * 1024 + col] = h16;  // cross-kernel
      if (hT_out && t == 63) hT_out[b * 1024 + col] = hn;           // cross-kernel
    }

    // ---- software grid barrier (128 participants; skip after last step)
    if (t != 63) {
      __threadfence();
      __syncthreads();
      if (tid == 0) {
        u32 a = __hip_atomic_fetch_add(bar_cnt, 1u, __ATOMIC_SEQ_CST,
                                       __HIP_MEMORY_SCOPE_AGENT);
        u32 want = (u32)(t + 1);
        if (a == (u32)t * 128u + 127u) {
          __hip_atomic_store(bar_flag, want, __ATOMIC_SEQ_CST,
                             __HIP_MEMORY_SCOPE_AGENT);
        } else {
          int guard = 0;
          while (__hip_atomic_load(bar_flag, __ATOMIC_SEQ_CST,
                                   __HIP_MEMORY_SCOPE_AGENT) < want) {
            __builtin_amdgcn_s_sleep(32);
            if (++guard > (1 << 16)) break;   // ~50ms safety valve
          }
        }
      }
      __syncthreads();
      __threadfence();
    }
  }
}

// ---------------------------------------------------------------------------
// mean/logvar/latent + hd0 = [latent|cond_e] @ W_st^T + b_st -> bf16 h0.
__global__ __launch_bounds__(256) void latent_hd0_kernel(
    const float* hT, const float* Wm, const float* bm,
    const float* Wl, const float* bl, const float* Wst, const float* bst,
    const float* eps, const float* ce, u16* hb0) {
  __shared__ float red[64][4];
  __shared__ float ml[64];
  __shared__ float lat[40];
  int b = blockIdx.x;
  int tid = threadIdx.x;
  int o = tid >> 2, p = tid & 3;
  const float* w = (o < 32) ? (Wm + (size_t)o * 1024) : (Wl + (size_t)(o - 32) * 1024);
  const float* h = hT + (size_t)b * 1024;
  float s = 0.f;
  for (int k = p * 256; k < p * 256 + 256; ++k) s += h[k] * w[k];
  red[o][p] = s;
  __syncthreads();
  if (tid < 64) {
    float v = red[tid][0] + red[tid][1] + red[tid][2] + red[tid][3];
    v += (tid < 32) ? bm[tid] : bl[tid - 32];
    ml[tid] = v;
  }
  __syncthreads();
  if (tid < 32) lat[tid] = eps[b * 32 + tid] * __expf(0.5f * ml[32 + tid]) + ml[tid];
  if (tid >= 32 && tid < 40) lat[tid] = ce[b * 8 + (tid - 32)];
  __syncthreads();
  for (int hc = tid; hc < 1024; hc += 256) {
    float s2 = bst[hc];
    const float* wr = Wst + (size_t)hc * 40;
#pragma unroll
    for (int j = 0; j < 40; ++j) s2 += lat[j] * wr[j];
    hb0[b * 1024 + hc] = f2bf(s2);
  }
}

// ---------------------------------------------------------------------------
extern "C" void kernel_launch(void* const* d_in, const int* in_sizes, int n_in,
                              void* d_out, int out_size, void* d_ws, size_t ws_size,
                              hipStream_t stream) {
  const int*   input_word = (const int*)d_in[0];
  const int*   cond       = (const int*)d_in[1];
  const float* emb_N      = (const float*)d_in[2];
  const float* Wih_N      = (const float*)d_in[3];
  const float* Whh_N      = (const float*)d_in[4];
  const float* bih_N      = (const float*)d_in[5];
  const float* bhh_N      = (const float*)d_in[6];
  const float* emb_D      = (const float*)d_in[7];
  const float* Wih_D      = (const float*)d_in[8];
  const float* Whh_D      = (const float*)d_in[9];
  const float* bih_D      = (const float*)d_in[10];
  const float* bhh_D      = (const float*)d_in[11];
  const float* emb_cond   = (const float*)d_in[12];
  const float* W_mean     = (const float*)d_in[13];
  const float* b_mean     = (const float*)d_in[14];
  const float* W_logvar   = (const float*)d_in[15];
  const float* b_logvar   = (const float*)d_in[16];
  const float* W_st       = (const float*)d_in[17];
  const float* b_st       = (const float*)d_in[18];
  const float* W_out      = (const float*)d_in[19];
  const float* b_out      = (const float*)d_in[20];
  const float* eps        = (const float*)d_in[21];
  float* out = (float*)d_out;

  char* ws = (char*)d_ws;
  size_t off = 0;
  auto alloc = [&](size_t b) { size_t p = off; off += (b + 255) & ~(size_t)255; return p; };
  u16*   wihN = (u16*)(ws + alloc(4096ull * 1024 * 2));
  u16*   whhN = (u16*)(ws + alloc(4096ull * 1024 * 2));
  u16*   wihD = (u16*)(ws + alloc(4096ull * 1024 * 2));
  u16*   whhD = (u16*)(ws + alloc(4096ull * 1024 * 2));
  u16*   wout = (u16*)(ws + alloc(32000ull * 1024 * 2));
  u16*   Xe   = (u16*)(ws + alloc(4096ull * 1024 * 2));
  u16*   Xd   = (u16*)(ws + alloc(4096ull * 1024 * 2));
  float* Xp   = (float*)(ws + alloc(4096ull * 4096 * 4));   // enc then dec
  u16*   hsd  = (u16*)(ws + alloc(4096ull * 1024 * 2));     // [b*64+t][1024]
  u16*   hb   = (u16*)(ws + alloc(2ull * 64 * 1024 * 2));   // bf16 h dbuf
  float* hf   = (float*)(ws + alloc(64ull * 1024 * 4));     // fp32 h_T (encoder)
  float* biasN = (float*)(ws + alloc(4096 * 4));
  float* biasD = (float*)(ws + alloc(4096 * 4));
  float* ce    = (float*)(ws + alloc(64 * 8 * 4));
  u32*   bar   = (u32*)(ws + alloc(512));   // [0]=cntE [32]=flagE [64]=cntD [96]=flagD
  if (off > ws_size) return;

  conv_all<<<48384, 256, 0, stream>>>(Wih_N, wihN, Whh_N, whhN,
                                      Wih_D, wihD, Whh_D, whhD, W_out, wout);
  prep_small<<<18, 256, 0, stream>>>(cond, emb_cond, bih_N, bhh_N, bih_D, bhh_D,
                                     ce, biasN, biasD, bar);
  gather_kernel<<<4096, 256, 0, stream>>>(emb_N, input_word, Xe, 0);
  gather_kernel<<<4096, 256, 0, stream>>>(emb_D, input_word, Xd, 1);
  init_enc<<<256, 256, 0, stream>>>(ce, hb);

  // encoder precompute + persistent recurrence
  gemm_bt_kernel<0><<<512, 512, 0, stream>>>(Xe, wihN, Xp, biasN, 4096, 1024);
  lstm_persist<<<128, 512, 0, stream>>>(whhN, Xp, hb, nullptr, hf,
                                        bar + 0, bar + 32);
  // latent + decoder h0 (writes hb[0]; decoder c0=0 is in-register)
  latent_hd0_kernel<<<64, 256, 0, stream>>>(hf, W_mean, b_mean, W_logvar, b_logvar,
                                            W_st, b_st, eps, ce, hb);
  // decoder precompute + persistent recurrence
  gemm_bt_kernel<0><<<512, 512, 0, stream>>>(Xd, wihD, Xp, biasD, 4096, 1024);
  lstm_persist<<<128, 512, 0, stream>>>(whhD, Xp, hb, hsd, nullptr,
                                        bar + 64, bar + 96);
  // logits[b][t][:] = hsd[b*64+t] @ W_out^T + b_out (per-XCD n-partition, NT)
  gemm_bt_kernel<1><<<4096, 512, 0, stream>>>(hsd, wout, out, b_out, 32000, 1024);
}

// Round 13
// 4984.958 us; speedup vs baseline: 1.0837x; 1.0837x over previous
//
#include <hip/hip_runtime.h>
#include <hip/hip_bf16.h>

typedef unsigned short u16;
typedef unsigned int   u32;
typedef unsigned long long u64;
typedef __attribute__((ext_vector_type(8))) short short8;   // 8 x bf16 (4 VGPRs)
typedef __attribute__((ext_vector_type(4))) float f32x4;

#define DEVINL static __device__ __forceinline__

// round-to-nearest-even f32 -> bf16
DEVINL u16 f2bf(float x) {
  u32 u = __float_as_uint(x);
  u32 r = (u + 0x7fffu + ((u >> 16) & 1u)) >> 16;
  return (u16)r;
}

// async global->LDS, 16B per lane. LDS dest = uniform base + lane*16.
#define GLD16(gp, lp) __builtin_amdgcn_global_load_lds(                     \
    (const __attribute__((address_space(1))) u32*)(gp),                     \
    (__attribute__((address_space(3))) u32*)(lp), 16, 0, 0)

// ---------------------------------------------------------------------------
// fp32 -> bf16 bulk convert, ALL five weight tensors in one launch.
__global__ __launch_bounds__(256) void conv_all(
    const float* __restrict__ s0, u16* __restrict__ d0,
    const float* __restrict__ s1, u16* __restrict__ d1,
    const float* __restrict__ s2, u16* __restrict__ d2,
    const float* __restrict__ s3, u16* __restrict__ d3,
    const float* __restrict__ s4, u16* __restrict__ d4) {
  const float* s; u16* d; int local;
  int blk = blockIdx.x;
  if (blk < 16384) {
    int p = blk >> 12; local = blk & 4095;
    s = (p == 0) ? s0 : (p == 1) ? s1 : (p == 2) ? s2 : s3;
    d = (p == 0) ? d0 : (p == 1) ? d1 : (p == 2) ? d2 : d3;
  } else {
    s = s4; d = d4; local = blk - 16384;
  }
  int i = local * 256 + threadIdx.x;
  float4 v = ((const float4*)s)[i];
  ushort4 o;
  o.x = f2bf(v.x); o.y = f2bf(v.y); o.z = f2bf(v.z); o.w = f2bf(v.w);
  ((ushort4*)d)[i] = o;
}

// cond_e gather + fused bias vectors (bih+bhh) + zero barrier state (512 words)
__global__ __launch_bounds__(256) void prep_small(
    const int* __restrict__ cond, const float* __restrict__ emb_cond,
    const float* __restrict__ bihN, const float* __restrict__ bhhN,
    const float* __restrict__ bihD, const float* __restrict__ bhhD,
    float* __restrict__ ce, float* __restrict__ biasN, float* __restrict__ biasD,
    u32* __restrict__ bar) {
  int tid = blockIdx.x * 256 + threadIdx.x;
  if (tid < 512) {
    int b = tid >> 3, j = tid & 7;
    ce[tid] = emb_cond[cond[b] * 8 + j];
  }
  int i = tid - 512;
  if (i >= 0 && i < 4096) {
    biasN[i] = bihN[i] + bhhN[i];
    biasD[i] = bihD[i] + bhhD[i];
  }
  int k = tid - 4608;
  if (k >= 0 && k < 512) bar[k] = 0;
}

// encoder h0 = [zeros(B,1016), cond_e] -> bf16 into hbuf[0]
__global__ __launch_bounds__(256) void init_enc(const float* __restrict__ ce,
                                                u16* __restrict__ hb0) {
  int tid = blockIdx.x * 256 + threadIdx.x;   // 64*1024
  int b = tid >> 10, col = tid & 1023;
  float v = (col >= 1016) ? ce[b * 8 + (col - 1016)] : 0.f;
  hb0[tid] = f2bf(v);
}

// embedding row gather -> bf16, X[t*64+b][1024]
__global__ __launch_bounds__(256) void gather_kernel(const float* __restrict__ emb,
                                                     const int* __restrict__ words,
                                                     u16* __restrict__ X, int dec) {
  int r = blockIdx.x;                    // r = t*64 + b
  int t = r >> 6, b = r & 63;
  int tok = dec ? ((t == 0) ? 0 : words[b * 64 + t - 1]) : words[b * 64 + t];
  float4 v = ((const float4*)(emb + (size_t)tok * 1024))[threadIdx.x];
  ushort4 o;
  o.x = f2bf(v.x); o.y = f2bf(v.y); o.z = f2bf(v.z); o.w = f2bf(v.w);
  ((ushort4*)(X + (size_t)r * 1024))[threadIdx.x] = o;
}

// ---------------------------------------------------------------------------
// C = A(MxK) * B(NxK)^T + bias, bf16 in, fp32 out. 256x128 tile, BK=32,
// 512 threads = 8 waves (4m x 2n). MODE 0: n-fast + XCD swizzle (Xp GEMMs).
// MODE 1 (logits): per-XCD n-partition, NT stores. (Identical to round 11.)
template <int MODE>
__global__ __launch_bounds__(512) void gemm_bt_kernel(
    const u16* __restrict__ A, const u16* __restrict__ B,
    float* __restrict__ C, const float* __restrict__ bias, int N, int K) {
  __shared__ u16 lA[256 * 32];   // 16KB
  __shared__ u16 lB[128 * 32];   // 8KB
  const int tid = threadIdx.x;
  const int lane = tid & 63;
  const int wid = tid >> 6;      // 0..7

  int tile_m, tile_n;
  if (MODE == 0) {
    const int nn = N >> 7;
    const int nwg = gridDim.x;
    const int orig = blockIdx.x;
    const int wgid = (orig & 7) * (nwg >> 3) + (orig >> 3);
    tile_m = (wgid / nn) * 256;
    tile_n = (wgid % nn) * 128;
  } else {
    const int i = blockIdx.x;        // 0..4095
    const int x = i & 7;             // XCD id
    const int k = i >> 3;
    const int mg = k >> 6;
    const int r  = k & 63;
    const int kn = r >> 1;
    const int mi = r & 1;
    const int tn = kn * 8 + x;
    if (tn >= 250) return;
    tile_m = (mg * 2 + mi) * 256;
    tile_n = tn * 128;
  }
  const int wm = wid >> 1, wn = wid & 1;

  const int ldr = lane >> 2;
  const int lko = (lane & 3) * 8;
  const int l15 = lane & 15;
  const int g4 = lane >> 4;

  f32x4 acc[4][4];
#pragma unroll
  for (int i = 0; i < 4; ++i)
#pragma unroll
    for (int j = 0; j < 4; ++j) acc[i][j] = (f32x4)0.f;

  const size_t aBase = (size_t)tile_m * K;
  const size_t bBase = (size_t)tile_n * K;

  for (int k0 = 0; k0 < K; k0 += 32) {
    __syncthreads();
#pragma unroll
    for (int q = 0; q < 2; ++q) {
      int ch = wid * 2 + q;
      int row = ch * 16 + ldr;
      GLD16(A + aBase + (size_t)row * K + k0 + lko, &lA[ch * 512]);
    }
    {
      int row = wid * 16 + ldr;
      GLD16(B + bBase + (size_t)row * K + k0 + lko, &lB[wid * 512]);
    }
    __syncthreads();
    short8 af[4], bf[4];
#pragma unroll
    for (int i = 0; i < 4; ++i)
      af[i] = *(const short8*)&lA[(wm * 64 + i * 16 + l15) * 32 + g4 * 8];
#pragma unroll
    for (int j = 0; j < 4; ++j)
      bf[j] = *(const short8*)&lB[(wn * 64 + j * 16 + l15) * 32 + g4 * 8];
#pragma unroll
    for (int i = 0; i < 4; ++i)
#pragma unroll
      for (int j = 0; j < 4; ++j)
        acc[i][j] = __builtin_amdgcn_mfma_f32_16x16x32_bf16(af[i], bf[j], acc[i][j], 0, 0, 0);
  }

#pragma unroll
  for (int i = 0; i < 4; ++i) {
    int row0 = tile_m + wm * 64 + i * 16 + (g4 << 2);
#pragma unroll
    for (int j = 0; j < 4; ++j) {
      int col = tile_n + wn * 64 + j * 16 + l15;
      float bv = bias[col];
#pragma unroll
      for (int e = 0; e < 4; ++e) {
        size_t o = (size_t)(row0 + e) * (size_t)N + col;
        float v = acc[i][j][e] + bv;
        if (MODE == 1) __builtin_nontemporal_store(v, &C[o]);
        else           C[o] = v;
      }
    }
  }
}

// ---------------------------------------------------------------------------
// PERSISTENT LSTM v2. Same proven-correct skeleton as round 12 (128 WGs x
// 512 thr x 80KB LDS -> 2x co-residency slack; Whh in VGPRs for all steps;
// agent-atomic write-through h stores). Two fixes for the 40us/step
// serialization measured in r12:
//  (1) staging reads via CACHED global_load_lds (r2's body) — coherent
//      because h stores are write-through and the post-barrier acquire
//      fence (__threadfence -> buffer_inv) invalidates stale L1/L2;
//  (2) distributed barrier: per-WG arrive word (parallel release stores,
//      no shared-address RMW), WG0 polls 128 words with RELAXED loads,
//      sets flag; all spin RELAXED + s_sleep(4), one acquire fence after.
__global__ __launch_bounds__(512, 1) void lstm_persist(
    const u16* __restrict__ Whh, const float* __restrict__ Xp,
    u16* __restrict__ hbuf,        // [2][64][1024] bf16 double buffer
    u16* __restrict__ hs_out,      // decoder: [b*64+t][1024] bf16, else null
    float* __restrict__ hT_out,    // encoder: [64][1024] fp32, else null
    u32* arrive, u32* flag) {
  __shared__ __align__(16) char smemA[65536];   // 32 rows x 2048B, swizzled
  __shared__ float lg[8][2][16][16];            // [wave][mtile][mrow][col]
  const int tid = threadIdx.x;      // 0..511
  const int lane = tid & 63;
  const int v = tid >> 6;           // wave 0..7
  const int gate = v >> 1;
  const int kh = v & 1;
  const int wgi = blockIdx.x;       // 0..127
  const int cg = wgi >> 1;          // col-group 0..63
  const int half = wgi & 1;         // batch half
  const int hc0 = cg * 16;
  const int b0 = half * 32;
  const int l15 = lane & 15;
  const int g4 = lane >> 4;

  // Whh fragments: loaded ONCE, live across all 64 steps (64 VGPRs)
  short8 breg[16];
  {
    const u16* Brow = Whh + (size_t)(gate * 1024 + hc0 + l15) * 1024
                          + kh * 512 + g4 * 8;
#pragma unroll
    for (int kk = 0; kk < 16; ++kk)
      breg[kk] = *(const short8*)(Brow + kk * 32);
  }

  // cell mapping: thread -> (bb = tid>>4 in 0..31, n = tid&15)
  const int bb = tid >> 4, n = tid & 15;
  const int b = b0 + bb, col = hc0 + n;
  float creg = 0.f;

  for (int t = 0; t < 64; ++t) {
    const char* rb = (const char*)(hbuf + (size_t)(t & 1) * 65536)
                   + (size_t)b0 * 2048;
    u32* wb32 = (u32*)(hbuf + (size_t)((t + 1) & 1) * 65536);

    // ---- stage h rows [b0, b0+32) -> swizzled LDS via CACHED GLD16
    //      (inverse-swizzled per-lane global source, linear wave dest)
#pragma unroll
    for (int q = 0; q < 8; ++q) {
      int o = q * 8192 + tid * 16;        // linear LDS byte offset
      int row = o >> 11;                  // 0..31
      int cb = o & 2047;
      const char* src = rb + row * 2048 + (cb ^ ((row & 7) << 4));
      GLD16(src, smemA + q * 8192 + v * 1024);
    }
    // ---- Xp prefetch for this thread's cell
    size_t xrow = (size_t)(t * 64 + b) * 4096 + col;
    float xg0 = __builtin_nontemporal_load(&Xp[xrow]);
    float xg1 = __builtin_nontemporal_load(&Xp[xrow + 1024]);
    float xg2 = __builtin_nontemporal_load(&Xp[xrow + 2048]);
    float xg3 = __builtin_nontemporal_load(&Xp[xrow + 3072]);
    __syncthreads();

    // ---- 32 MFMAs/wave: 2 m-tiles x 16 k-steps of this wave's K-half
    f32x4 acc0 = (f32x4)0.f, acc1 = (f32x4)0.f;
#pragma unroll
    for (int kk = 0; kk < 16; ++kk) {
      int ct = (kh * 16 + kk) * 64 + g4 * 16;
      int sw = ct ^ ((l15 & 7) << 4);     // rows 16+l15 share (row&7)==(l15&7)
      const short8 a0 = *(const short8*)(smemA + l15 * 2048 + sw);
      const short8 a1 = *(const short8*)(smemA + (16 + l15) * 2048 + sw);
      acc0 = __builtin_amdgcn_mfma_f32_16x16x32_bf16(a0, breg[kk], acc0, 0, 0, 0);
      acc1 = __builtin_amdgcn_mfma_f32_16x16x32_bf16(a1, breg[kk], acc1, 0, 0, 0);
    }
    {
      int m0 = g4 * 4;
#pragma unroll
      for (int e = 0; e < 4; ++e) {
        lg[v][0][m0 + e][l15] = acc0[e];
        lg[v][1][m0 + e][l15] = acc1[e];
      }
    }
    __syncthreads();

    // ---- cell update: 1 cell per thread
    {
      int m = bb >> 4, r = bb & 15;
      float gi = lg[0][m][r][n] + lg[1][m][r][n] + xg0;
      float gf = lg[2][m][r][n] + lg[3][m][r][n] + xg1;
      float gg = lg[4][m][r][n] + lg[5][m][r][n] + xg2;
      float go = lg[6][m][r][n] + lg[7][m][r][n] + xg3;
      float si = 1.f / (1.f + __expf(-gi));
      float sf = 1.f / (1.f + __expf(-gf));
      float so = 1.f / (1.f + __expf(-go));
      float tg = tanhf(gg);
      float cn = sf * creg + si * tg;
      float hn = so * tanhf(cn);
      creg = cn;
      u16 h16 = f2bf(hn);
      // pack adjacent-n pair via shfl (partner lane = lane^1)
      u32 mine = h16;
      u32 other = (u32)__shfl_xor((int)mine, 1);
      if (!(n & 1)) {
        u32 pk = mine | (other << 16);
        size_t wi = ((size_t)b * 1024 + col) >> 1;
        __hip_atomic_store(wb32 + wi, pk, __ATOMIC_RELAXED,
                           __HIP_MEMORY_SCOPE_AGENT);
      }
      if (hs_out) hs_out[((size_t)b * 64 + t) * 1024 + col] = h16;  // cross-kernel
      if (hT_out && t == 63) hT_out[b * 1024 + col] = hn;           // cross-kernel
    }

    // ---- distributed software grid barrier (skip after last step)
    if (t != 63) {
      u32 want = (u32)(t + 1);
      __threadfence();                 // drain h stores (release)
      __syncthreads();
      if (tid == 0)
        __hip_atomic_store(&arrive[wgi], want, __ATOMIC_RELEASE,
                           __HIP_MEMORY_SCOPE_AGENT);
      if (wgi == 0) {
        if (tid < 128) {
          int guard = 0;
          while (__hip_atomic_load(&arrive[tid], __ATOMIC_RELAXED,
                                   __HIP_MEMORY_SCOPE_AGENT) < want) {
            __builtin_amdgcn_s_sleep(4);
            if (++guard > (1 << 20)) break;   // safety valve
          }
        }
        __syncthreads();
        if (tid == 0)
          __hip_atomic_store(flag, want, __ATOMIC_RELEASE,
                             __HIP_MEMORY_SCOPE_AGENT);
      }
      if (tid == 0) {
        int guard = 0;
        while (__hip_atomic_load(flag, __ATOMIC_RELAXED,
                                 __HIP_MEMORY_SCOPE_AGENT) < want) {
          __builtin_amdgcn_s_sleep(4);
          if (++guard > (1 << 20)) break;     // safety valve
        }
      }
      __syncthreads();
      __threadfence();                 // acquire: invalidate L1/L2
    }
  }
}

// ---------------------------------------------------------------------------
// mean/logvar/latent + hd0 = [latent|cond_e] @ W_st^T + b_st -> bf16 h0.
__global__ __launch_bounds__(256) void latent_hd0_kernel(
    const float* hT, const float* Wm, const float* bm,
    const float* Wl, const float* bl, const float* Wst, const float* bst,
    const float* eps, const float* ce, u16* hb0) {
  __shared__ float red[64][4];
  __shared__ float ml[64];
  __shared__ float lat[40];
  int b = blockIdx.x;
  int tid = threadIdx.x;
  int o = tid >> 2, p = tid & 3;
  const float* w = (o < 32) ? (Wm + (size_t)o * 1024) : (Wl + (size_t)(o - 32) * 1024);
  const float* h = hT + (size_t)b * 1024;
  float s = 0.f;
  for (int k = p * 256; k < p * 256 + 256; ++k) s += h[k] * w[k];
  red[o][p] = s;
  __syncthreads();
  if (tid < 64) {
    float v = red[tid][0] + red[tid][1] + red[tid][2] + red[tid][3];
    v += (tid < 32) ? bm[tid] : bl[tid - 32];
    ml[tid] = v;
  }
  __syncthreads();
  if (tid < 32) lat[tid] = eps[b * 32 + tid] * __expf(0.5f * ml[32 + tid]) + ml[tid];
  if (tid >= 32 && tid < 40) lat[tid] = ce[b * 8 + (tid - 32)];
  __syncthreads();
  for (int hc = tid; hc < 1024; hc += 256) {
    float s2 = bst[hc];
    const float* wr = Wst + (size_t)hc * 40;
#pragma unroll
    for (int j = 0; j < 40; ++j) s2 += lat[j] * wr[j];
    hb0[b * 1024 + hc] = f2bf(s2);
  }
}

// ---------------------------------------------------------------------------
extern "C" void kernel_launch(void* const* d_in, const int* in_sizes, int n_in,
                              void* d_out, int out_size, void* d_ws, size_t ws_size,
                              hipStream_t stream) {
  const int*   input_word = (const int*)d_in[0];
  const int*   cond       = (const int*)d_in[1];
  const float* emb_N      = (const float*)d_in[2];
  const float* Wih_N      = (const float*)d_in[3];
  const float* Whh_N      = (const float*)d_in[4];
  const float* bih_N      = (const float*)d_in[5];
  const float* bhh_N      = (const float*)d_in[6];
  const float* emb_D      = (const float*)d_in[7];
  const float* Wih_D      = (const float*)d_in[8];
  const float* Whh_D      = (const float*)d_in[9];
  const float* bih_D      = (const float*)d_in[10];
  const float* bhh_D      = (const float*)d_in[11];
  const float* emb_cond   = (const float*)d_in[12];
  const float* W_mean     = (const float*)d_in[13];
  const float* b_mean     = (const float*)d_in[14];
  const float* W_logvar   = (const float*)d_in[15];
  const float* b_logvar   = (const float*)d_in[16];
  const float* W_st       = (const float*)d_in[17];
  const float* b_st       = (const float*)d_in[18];
  const float* W_out      = (const float*)d_in[19];
  const float* b_out      = (const float*)d_in[20];
  const float* eps        = (const float*)d_in[21];
  float* out = (float*)d_out;

  char* ws = (char*)d_ws;
  size_t off = 0;
  auto alloc = [&](size_t b) { size_t p = off; off += (b + 255) & ~(size_t)255; return p; };
  u16*   wihN = (u16*)(ws + alloc(4096ull * 1024 * 2));
  u16*   whhN = (u16*)(ws + alloc(4096ull * 1024 * 2));
  u16*   wihD = (u16*)(ws + alloc(4096ull * 1024 * 2));
  u16*   whhD = (u16*)(ws + alloc(4096ull * 1024 * 2));
  u16*   wout = (u16*)(ws + alloc(32000ull * 1024 * 2));
  u16*   Xe   = (u16*)(ws + alloc(4096ull * 1024 * 2));
  u16*   Xd   = (u16*)(ws + alloc(4096ull * 1024 * 2));
  float* Xp   = (float*)(ws + alloc(4096ull * 4096 * 4));   // enc then dec
  u16*   hsd  = (u16*)(ws + alloc(4096ull * 1024 * 2));     // [b*64+t][1024]
  u16*   hb   = (u16*)(ws + alloc(2ull * 64 * 1024 * 2));   // bf16 h dbuf
  float* hf   = (float*)(ws + alloc(64ull * 1024 * 4));     // fp32 h_T (encoder)
  float* biasN = (float*)(ws + alloc(4096 * 4));
  float* biasD = (float*)(ws + alloc(4096 * 4));
  float* ce    = (float*)(ws + alloc(64 * 8 * 4));
  u32*   bar   = (u32*)(ws + alloc(2048));
  // bar layout: enc arrive = bar[0..127], enc flag = bar[160],
  //             dec arrive = bar[256..383], dec flag = bar[416]
  if (off > ws_size) return;

  conv_all<<<48384, 256, 0, stream>>>(Wih_N, wihN, Whh_N, whhN,
                                      Wih_D, wihD, Whh_D, whhD, W_out, wout);
  prep_small<<<20, 256, 0, stream>>>(cond, emb_cond, bih_N, bhh_N, bih_D, bhh_D,
                                     ce, biasN, biasD, bar);
  gather_kernel<<<4096, 256, 0, stream>>>(emb_N, input_word, Xe, 0);
  gather_kernel<<<4096, 256, 0, stream>>>(emb_D, input_word, Xd, 1);
  init_enc<<<256, 256, 0, stream>>>(ce, hb);

  // encoder precompute + persistent recurrence
  gemm_bt_kernel<0><<<512, 512, 0, stream>>>(Xe, wihN, Xp, biasN, 4096, 1024);
  lstm_persist<<<128, 512, 0, stream>>>(whhN, Xp, hb, nullptr, hf,
                                        bar + 0, bar + 160);
  // latent + decoder h0 (writes hb[0]; decoder c0=0 is in-register)
  latent_hd0_kernel<<<64, 256, 0, stream>>>(hf, W_mean, b_mean, W_logvar, b_logvar,
                                            W_st, b_st, eps, ce, hb);
  // decoder precompute + persistent recurrence
  gemm_bt_kernel<0><<<512, 512, 0, stream>>>(Xd, wihD, Xp, biasD, 4096, 1024);
  lstm_persist<<<128, 512, 0, stream>>>(whhD, Xp, hb, hsd, nullptr,
                                        bar + 256, bar + 416);
  // logits[b][t][:] = hsd[b*64+t] @ W_out^T + b_out (per-XCD n-partition, NT)
  gemm_bt_kernel<1><<<4096, 512, 0, stream>>>(hsd, wout, out, b_out, 32000, 1024);
}

// Round 14
// 1114.882 us; speedup vs baseline: 4.8457x; 4.4713x over previous
//
#include <hip/hip_runtime.h>
#include <hip/hip_bf16.h>

typedef unsigned short u16;
typedef unsigned int   u32;
typedef unsigned long long u64;
typedef __attribute__((ext_vector_type(8))) short short8;   // 8 x bf16 (4 VGPRs)
typedef __attribute__((ext_vector_type(4))) float f32x4;

#define DEVINL static __device__ __forceinline__

// round-to-nearest-even f32 -> bf16
DEVINL u16 f2bf(float x) {
  u32 u = __float_as_uint(x);
  u32 r = (u + 0x7fffu + ((u >> 16) & 1u)) >> 16;
  return (u16)r;
}

// async global->LDS, 16B per lane. LDS dest = uniform base + lane*16.
#define GLD16(gp, lp) __builtin_amdgcn_global_load_lds(                     \
    (const __attribute__((address_space(1))) u32*)(gp),                     \
    (__attribute__((address_space(3))) u32*)(lp), 16, 0, 0)

// ---------------------------------------------------------------------------
// fp32 -> bf16 bulk convert, ALL five weight tensors in one launch.
__global__ __launch_bounds__(256) void conv_all(
    const float* __restrict__ s0, u16* __restrict__ d0,
    const float* __restrict__ s1, u16* __restrict__ d1,
    const float* __restrict__ s2, u16* __restrict__ d2,
    const float* __restrict__ s3, u16* __restrict__ d3,
    const float* __restrict__ s4, u16* __restrict__ d4) {
  const float* s; u16* d; int local;
  int blk = blockIdx.x;
  if (blk < 16384) {
    int p = blk >> 12; local = blk & 4095;
    s = (p == 0) ? s0 : (p == 1) ? s1 : (p == 2) ? s2 : s3;
    d = (p == 0) ? d0 : (p == 1) ? d1 : (p == 2) ? d2 : d3;
  } else {
    s = s4; d = d4; local = blk - 16384;
  }
  int i = local * 256 + threadIdx.x;
  float4 v = ((const float4*)s)[i];
  ushort4 o;
  o.x = f2bf(v.x); o.y = f2bf(v.y); o.z = f2bf(v.z); o.w = f2bf(v.w);
  ((ushort4*)d)[i] = o;
}

// cond_e gather + fused bias vectors (bih+bhh) + zero barrier state (512 words)
__global__ __launch_bounds__(256) void prep_small(
    const int* __restrict__ cond, const float* __restrict__ emb_cond,
    const float* __restrict__ bihN, const float* __restrict__ bhhN,
    const float* __restrict__ bihD, const float* __restrict__ bhhD,
    float* __restrict__ ce, float* __restrict__ biasN, float* __restrict__ biasD,
    u32* __restrict__ bar) {
  int tid = blockIdx.x * 256 + threadIdx.x;
  if (tid < 512) {
    int b = tid >> 3, j = tid & 7;
    ce[tid] = emb_cond[cond[b] * 8 + j];
  }
  int i = tid - 512;
  if (i >= 0 && i < 4096) {
    biasN[i] = bihN[i] + bhhN[i];
    biasD[i] = bihD[i] + bhhD[i];
  }
  int k = tid - 4608;
  if (k >= 0 && k < 512) bar[k] = 0;
}

// encoder h0 = [zeros(B,1016), cond_e] -> bf16 into hbuf[0]
__global__ __launch_bounds__(256) void init_enc(const float* __restrict__ ce,
                                                u16* __restrict__ hb0) {
  int tid = blockIdx.x * 256 + threadIdx.x;   // 64*1024
  int b = tid >> 10, col = tid & 1023;
  float v = (col >= 1016) ? ce[b * 8 + (col - 1016)] : 0.f;
  hb0[tid] = f2bf(v);
}

// embedding row gather -> bf16, X[t*64+b][1024]
__global__ __launch_bounds__(256) void gather_kernel(const float* __restrict__ emb,
                                                     const int* __restrict__ words,
                                                     u16* __restrict__ X, int dec) {
  int r = blockIdx.x;                    // r = t*64 + b
  int t = r >> 6, b = r & 63;
  int tok = dec ? ((t == 0) ? 0 : words[b * 64 + t - 1]) : words[b * 64 + t];
  float4 v = ((const float4*)(emb + (size_t)tok * 1024))[threadIdx.x];
  ushort4 o;
  o.x = f2bf(v.x); o.y = f2bf(v.y); o.z = f2bf(v.z); o.w = f2bf(v.w);
  ((ushort4*)(X + (size_t)r * 1024))[threadIdx.x] = o;
}

// ---------------------------------------------------------------------------
// C = A(MxK) * B(NxK)^T + bias, bf16 in, fp32 out. 256x128 tile, BK=32,
// 512 threads = 8 waves (4m x 2n). MODE 0: n-fast + XCD swizzle (Xp GEMMs).
// MODE 1 (logits): per-XCD n-partition, NT stores. (Identical to round 11.)
template <int MODE>
__global__ __launch_bounds__(512) void gemm_bt_kernel(
    const u16* __restrict__ A, const u16* __restrict__ B,
    float* __restrict__ C, const float* __restrict__ bias, int N, int K) {
  __shared__ u16 lA[256 * 32];   // 16KB
  __shared__ u16 lB[128 * 32];   // 8KB
  const int tid = threadIdx.x;
  const int lane = tid & 63;
  const int wid = tid >> 6;      // 0..7

  int tile_m, tile_n;
  if (MODE == 0) {
    const int nn = N >> 7;
    const int nwg = gridDim.x;
    const int orig = blockIdx.x;
    const int wgid = (orig & 7) * (nwg >> 3) + (orig >> 3);
    tile_m = (wgid / nn) * 256;
    tile_n = (wgid % nn) * 128;
  } else {
    const int i = blockIdx.x;        // 0..4095
    const int x = i & 7;             // XCD id
    const int k = i >> 3;
    const int mg = k >> 6;
    const int r  = k & 63;
    const int kn = r >> 1;
    const int mi = r & 1;
    const int tn = kn * 8 + x;
    if (tn >= 250) return;
    tile_m = (mg * 2 + mi) * 256;
    tile_n = tn * 128;
  }
  const int wm = wid >> 1, wn = wid & 1;

  const int ldr = lane >> 2;
  const int lko = (lane & 3) * 8;
  const int l15 = lane & 15;
  const int g4 = lane >> 4;

  f32x4 acc[4][4];
#pragma unroll
  for (int i = 0; i < 4; ++i)
#pragma unroll
    for (int j = 0; j < 4; ++j) acc[i][j] = (f32x4)0.f;

  const size_t aBase = (size_t)tile_m * K;
  const size_t bBase = (size_t)tile_n * K;

  for (int k0 = 0; k0 < K; k0 += 32) {
    __syncthreads();
#pragma unroll
    for (int q = 0; q < 2; ++q) {
      int ch = wid * 2 + q;
      int row = ch * 16 + ldr;
      GLD16(A + aBase + (size_t)row * K + k0 + lko, &lA[ch * 512]);
    }
    {
      int row = wid * 16 + ldr;
      GLD16(B + bBase + (size_t)row * K + k0 + lko, &lB[wid * 512]);
    }
    __syncthreads();
    short8 af[4], bf[4];
#pragma unroll
    for (int i = 0; i < 4; ++i)
      af[i] = *(const short8*)&lA[(wm * 64 + i * 16 + l15) * 32 + g4 * 8];
#pragma unroll
    for (int j = 0; j < 4; ++j)
      bf[j] = *(const short8*)&lB[(wn * 64 + j * 16 + l15) * 32 + g4 * 8];
#pragma unroll
    for (int i = 0; i < 4; ++i)
#pragma unroll
      for (int j = 0; j < 4; ++j)
        acc[i][j] = __builtin_amdgcn_mfma_f32_16x16x32_bf16(af[i], bf[j], acc[i][j], 0, 0, 0);
  }

#pragma unroll
  for (int i = 0; i < 4; ++i) {
    int row0 = tile_m + wm * 64 + i * 16 + (g4 << 2);
#pragma unroll
    for (int j = 0; j < 4; ++j) {
      int col = tile_n + wn * 64 + j * 16 + l15;
      float bv = bias[col];
#pragma unroll
      for (int e = 0; e < 4; ++e) {
        size_t o = (size_t)(row0 + e) * (size_t)N + col;
        float v = acc[i][j][e] + bv;
        if (MODE == 1) __builtin_nontemporal_store(v, &C[o]);
        else           C[o] = v;
      }
    }
  }
}

// ---------------------------------------------------------------------------
// CLUSTERED PERSISTENT LSTM. Key insight: the recurrence is independent per
// batch row (h_{t+1}[b,:] depends only on h_t[b,:]) -> NO grid-wide barrier.
// 4 independent clusters x 16 batch rows; 32 WGs/cluster, WG owns 32 h-cols
// (full K). Whh slice in 128 VGPRs/wave for all 64 steps. Per step: stage
// cluster h-slab (16x1024, 32KB) via agent-atomic loads -> swizzled LDS;
// 32 MFMAs/wave; cell update in regs; packed u32 agent-atomic h stores.
// FENCE-FREE cluster barrier (no buffer_wbl2/inv — the r12/r13 36us/step
// killer): per-wave `s_waitcnt vmcnt(0)` orders write-through stores, then
// RELAXED arrive store; leader WG polls 32 arrive words; RELAXED flag.
// Atomic h loads bypass stale caches so no acquire invalidate is needed.
// 128 WGs x 40KB LDS: co-residency trivially guaranteed (128 < 256 CUs).
__global__ __launch_bounds__(512, 1) void lstm_cluster(
    const u16* __restrict__ Whh, const float* __restrict__ Xp,
    u16* __restrict__ hbuf,        // [2][64][1024] bf16 double buffer
    u16* __restrict__ hs_out,      // decoder: [b*64+t][1024] bf16, else null
    float* __restrict__ hT_out,    // encoder: [64][1024] fp32, else null
    u32* arrive, u32* flags) {     // arrive[128], flags[4]
  __shared__ __align__(16) char smemA[32768];   // 16 rows x 2048B, swizzled
  __shared__ float lg[8][16][16];               // [wave][batchrow][col16]
  const int tid = threadIdx.x;      // 0..511
  const int lane = tid & 63;
  const int v = tid >> 6;           // wave 0..7
  const int gate = v >> 1;
  const int ch = v & 1;             // col-half of the WG's 32 cols
  const int wgi = blockIdx.x;       // 0..127
  const int c = wgi >> 5;           // cluster 0..3 (owns batch rows c*16..+16)
  const int j = wgi & 31;           // WG within cluster (owns cols j*32..+32)
  const int b0 = c * 16, col0 = j * 32;
  const int l15 = lane & 15, g4 = lane >> 4;

  // Whh fragments: loaded ONCE, live across all 64 steps (128 VGPRs)
  short8 breg[32];
  {
    const u16* Brow = Whh + (size_t)(gate * 1024 + col0 + ch * 16 + l15) * 1024
                          + g4 * 8;
#pragma unroll
    for (int kk = 0; kk < 32; ++kk)
      breg[kk] = *(const short8*)(Brow + kk * 32);
  }

  // cell mapping: 512 threads = 16 rows x 32 cols
  const int crow = tid >> 5, colw = tid & 31;
  const int bg = b0 + crow, cgl = col0 + colw;
  const int ch2 = colw >> 4, cw = colw & 15;
  float creg = 0.f;

  for (int t = 0; t < 64; ++t) {
    const char* rbase = (const char*)(hbuf + (size_t)(t & 1) * 65536)
                      + (size_t)b0 * 2048;
    u32* wb32 = (u32*)(hbuf + (size_t)((t + 1) & 1) * 65536);

    // ---- Xp prefetch (independent; issues first)
    size_t xrow = (size_t)(t * 64 + bg) * 4096 + cgl;
    float xg0 = __builtin_nontemporal_load(&Xp[xrow]);
    float xg1 = __builtin_nontemporal_load(&Xp[xrow + 1024]);
    float xg2 = __builtin_nontemporal_load(&Xp[xrow + 2048]);
    float xg3 = __builtin_nontemporal_load(&Xp[xrow + 3072]);

    // ---- stage h slab (16 rows x 1024 cols) -> swizzled LDS, atomic loads
#pragma unroll
    for (int q = 0; q < 4; ++q) {
      int g = q * 512 + tid;              // 16B chunk id 0..2047
      int row = g >> 7;                   // 0..15
      int cb = (g & 127) * 16;            // byte col in row
      const u64* src = (const u64*)(rbase + (size_t)row * 2048 + cb);
      u64 lo = __hip_atomic_load(src,     __ATOMIC_RELAXED, __HIP_MEMORY_SCOPE_AGENT);
      u64 hi = __hip_atomic_load(src + 1, __ATOMIC_RELAXED, __HIP_MEMORY_SCOPE_AGENT);
      u64* d = (u64*)(smemA + row * 2048 + (cb ^ ((row & 7) << 4)));
      d[0] = lo; d[1] = hi;
    }
    __syncthreads();

    // ---- 32 MFMAs/wave (4 chains), A from swizzled LDS, B from regs
    f32x4 a4[4] = {(f32x4)0.f, (f32x4)0.f, (f32x4)0.f, (f32x4)0.f};
#pragma unroll
    for (int kk = 0; kk < 32; ++kk) {
      int cb2 = kk * 64 + g4 * 16;
      const short8 a = *(const short8*)(smemA + l15 * 2048 + (cb2 ^ ((l15 & 7) << 4)));
      a4[kk & 3] = __builtin_amdgcn_mfma_f32_16x16x32_bf16(a, breg[kk], a4[kk & 3], 0, 0, 0);
    }
    f32x4 asum = a4[0] + a4[1] + a4[2] + a4[3];
    {
      int m = g4 * 4;
#pragma unroll
      for (int e = 0; e < 4; ++e) lg[v][m + e][l15] = asum[e];
    }
    __syncthreads();

    // ---- cell update: 1 cell per thread
    {
      float gi = lg[0 + ch2][crow][cw] + xg0;
      float gf = lg[2 + ch2][crow][cw] + xg1;
      float gg = lg[4 + ch2][crow][cw] + xg2;
      float go = lg[6 + ch2][crow][cw] + xg3;
      float si = 1.f / (1.f + __expf(-gi));
      float sf = 1.f / (1.f + __expf(-gf));
      float so = 1.f / (1.f + __expf(-go));
      float tg = tanhf(gg);
      float cn = sf * creg + si * tg;
      float hn = so * tanhf(cn);
      creg = cn;
      u16 h16 = f2bf(hn);
      u32 mine = h16;
      u32 other = (u32)__shfl_xor((int)mine, 1);
      if (!(colw & 1)) {
        u32 pk = mine | (other << 16);
        __hip_atomic_store(wb32 + (((size_t)bg * 1024 + cgl) >> 1), pk,
                           __ATOMIC_RELAXED, __HIP_MEMORY_SCOPE_AGENT);
      }
      if (hs_out) hs_out[((size_t)bg * 64 + t) * 1024 + cgl] = h16;  // cross-kernel
      if (hT_out && t == 63) hT_out[bg * 1024 + cgl] = hn;           // cross-kernel
    }

    // ---- fence-free cluster barrier (32 WGs; skip after last step)
    if (t != 63) {
      u32 want = (u32)(t + 1);
      asm volatile("s_waitcnt vmcnt(0)" ::: "memory");   // h stores at coherence pt
      __syncthreads();
      if (tid == 0)
        __hip_atomic_store(&arrive[wgi], want, __ATOMIC_RELAXED,
                           __HIP_MEMORY_SCOPE_AGENT);
      if (j == 0) {                       // leader WG of cluster c
        if (tid < 32) {
          int guard = 0;
          while (__hip_atomic_load(&arrive[c * 32 + tid], __ATOMIC_RELAXED,
                                   __HIP_MEMORY_SCOPE_AGENT) < want) {
            __builtin_amdgcn_s_sleep(2);
            if (++guard > (1 << 20)) break;   // safety valve
          }
        }
        __syncthreads();
        if (tid == 0)
          __hip_atomic_store(&flags[c], want, __ATOMIC_RELAXED,
                             __HIP_MEMORY_SCOPE_AGENT);
      }
      if (tid == 0) {
        int guard = 0;
        while (__hip_atomic_load(&flags[c], __ATOMIC_RELAXED,
                                 __HIP_MEMORY_SCOPE_AGENT) < want) {
          __builtin_amdgcn_s_sleep(2);
          if (++guard > (1 << 20)) break;     // safety valve
        }
      }
      __syncthreads();
    }
  }
}

// ---------------------------------------------------------------------------
// mean/logvar/latent + hd0 = [latent|cond_e] @ W_st^T + b_st -> bf16 h0.
__global__ __launch_bounds__(256) void latent_hd0_kernel(
    const float* hT, const float* Wm, const float* bm,
    const float* Wl, const float* bl, const float* Wst, const float* bst,
    const float* eps, const float* ce, u16* hb0) {
  __shared__ float red[64][4];
  __shared__ float ml[64];
  __shared__ float lat[40];
  int b = blockIdx.x;
  int tid = threadIdx.x;
  int o = tid >> 2, p = tid & 3;
  const float* w = (o < 32) ? (Wm + (size_t)o * 1024) : (Wl + (size_t)(o - 32) * 1024);
  const float* h = hT + (size_t)b * 1024;
  float s = 0.f;
  for (int k = p * 256; k < p * 256 + 256; ++k) s += h[k] * w[k];
  red[o][p] = s;
  __syncthreads();
  if (tid < 64) {
    float v = red[tid][0] + red[tid][1] + red[tid][2] + red[tid][3];
    v += (tid < 32) ? bm[tid] : bl[tid - 32];
    ml[tid] = v;
  }
  __syncthreads();
  if (tid < 32) lat[tid] = eps[b * 32 + tid] * __expf(0.5f * ml[32 + tid]) + ml[tid];
  if (tid >= 32 && tid < 40) lat[tid] = ce[b * 8 + (tid - 32)];
  __syncthreads();
  for (int hc = tid; hc < 1024; hc += 256) {
    float s2 = bst[hc];
    const float* wr = Wst + (size_t)hc * 40;
#pragma unroll
    for (int j = 0; j < 40; ++j) s2 += lat[j] * wr[j];
    hb0[b * 1024 + hc] = f2bf(s2);
  }
}

// ---------------------------------------------------------------------------
extern "C" void kernel_launch(void* const* d_in, const int* in_sizes, int n_in,
                              void* d_out, int out_size, void* d_ws, size_t ws_size,
                              hipStream_t stream) {
  const int*   input_word = (const int*)d_in[0];
  const int*   cond       = (const int*)d_in[1];
  const float* emb_N      = (const float*)d_in[2];
  const float* Wih_N      = (const float*)d_in[3];
  const float* Whh_N      = (const float*)d_in[4];
  const float* bih_N      = (const float*)d_in[5];
  const float* bhh_N      = (const float*)d_in[6];
  const float* emb_D      = (const float*)d_in[7];
  const float* Wih_D      = (const float*)d_in[8];
  const float* Whh_D      = (const float*)d_in[9];
  const float* bih_D      = (const float*)d_in[10];
  const float* bhh_D      = (const float*)d_in[11];
  const float* emb_cond   = (const float*)d_in[12];
  const float* W_mean     = (const float*)d_in[13];
  const float* b_mean     = (const float*)d_in[14];
  const float* W_logvar   = (const float*)d_in[15];
  const float* b_logvar   = (const float*)d_in[16];
  const float* W_st       = (const float*)d_in[17];
  const float* b_st       = (const float*)d_in[18];
  const float* W_out      = (const float*)d_in[19];
  const float* b_out      = (const float*)d_in[20];
  const float* eps        = (const float*)d_in[21];
  float* out = (float*)d_out;

  char* ws = (char*)d_ws;
  size_t off = 0;
  auto alloc = [&](size_t b) { size_t p = off; off += (b + 255) & ~(size_t)255; return p; };
  u16*   wihN = (u16*)(ws + alloc(4096ull * 1024 * 2));
  u16*   whhN = (u16*)(ws + alloc(4096ull * 1024 * 2));
  u16*   wihD = (u16*)(ws + alloc(4096ull * 1024 * 2));
  u16*   whhD = (u16*)(ws + alloc(4096ull * 1024 * 2));
  u16*   wout = (u16*)(ws + alloc(32000ull * 1024 * 2));
  u16*   Xe   = (u16*)(ws + alloc(4096ull * 1024 * 2));
  u16*   Xd   = (u16*)(ws + alloc(4096ull * 1024 * 2));
  float* Xp   = (float*)(ws + alloc(4096ull * 4096 * 4));   // enc then dec
  u16*   hsd  = (u16*)(ws + alloc(4096ull * 1024 * 2));     // [b*64+t][1024]
  u16*   hb   = (u16*)(ws + alloc(2ull * 64 * 1024 * 2));   // bf16 h dbuf
  float* hf   = (float*)(ws + alloc(64ull * 1024 * 4));     // fp32 h_T (encoder)
  float* biasN = (float*)(ws + alloc(4096 * 4));
  float* biasD = (float*)(ws + alloc(4096 * 4));
  float* ce    = (float*)(ws + alloc(64 * 8 * 4));
  u32*   bar   = (u32*)(ws + alloc(2048));
  // bar: enc arrive bar[0..127], enc flags bar[128..131],
  //      dec arrive bar[256..383], dec flags bar[384..387]
  if (off > ws_size) return;

  conv_all<<<48384, 256, 0, stream>>>(Wih_N, wihN, Whh_N, whhN,
                                      Wih_D, wihD, Whh_D, whhD, W_out, wout);
  prep_small<<<20, 256, 0, stream>>>(cond, emb_cond, bih_N, bhh_N, bih_D, bhh_D,
                                     ce, biasN, biasD, bar);
  gather_kernel<<<4096, 256, 0, stream>>>(emb_N, input_word, Xe, 0);
  gather_kernel<<<4096, 256, 0, stream>>>(emb_D, input_word, Xd, 1);
  init_enc<<<256, 256, 0, stream>>>(ce, hb);

  // encoder precompute + clustered persistent recurrence
  gemm_bt_kernel<0><<<512, 512, 0, stream>>>(Xe, wihN, Xp, biasN, 4096, 1024);
  lstm_cluster<<<128, 512, 0, stream>>>(whhN, Xp, hb, nullptr, hf,
                                        bar + 0, bar + 128);
  // latent + decoder h0 (writes hb[0]; decoder c0=0 is in-register)
  latent_hd0_kernel<<<64, 256, 0, stream>>>(hf, W_mean, b_mean, W_logvar, b_logvar,
                                            W_st, b_st, eps, ce, hb);
  // decoder precompute + clustered persistent recurrence
  gemm_bt_kernel<0><<<512, 512, 0, stream>>>(Xd, wihD, Xp, biasD, 4096, 1024);
  lstm_cluster<<<128, 512, 0, stream>>>(whhD, Xp, hb, hsd, nullptr,
                                        bar + 256, bar + 384);
  // logits[b][t][:] = hsd[b*64+t] @ W_out^T + b_out (per-XCD n-partition, NT)
  gemm_bt_kernel<1><<<4096, 512, 0, stream>>>(hsd, wout, out, b_out, 32000, 1024);
}

// Round 15
// 1065.960 us; speedup vs baseline: 5.0681x; 1.0459x over previous
//
#include <hip/hip_runtime.h>
#include <hip/hip_bf16.h>

typedef unsigned short u16;
typedef unsigned int   u32;
typedef unsigned long long u64;
typedef __attribute__((ext_vector_type(8))) short short8;   // 8 x bf16 (4 VGPRs)
typedef __attribute__((ext_vector_type(4))) float f32x4;

#define DEVINL static __device__ __forceinline__

// round-to-nearest-even f32 -> bf16
DEVINL u16 f2bf(float x) {
  u32 u = __float_as_uint(x);
  u32 r = (u + 0x7fffu + ((u >> 16) & 1u)) >> 16;
  return (u16)r;
}

// async global->LDS, 16B per lane. LDS dest = uniform base + lane*16.
#define GLD16(gp, lp) __builtin_amdgcn_global_load_lds(                     \
    (const __attribute__((address_space(1))) u32*)(gp),                     \
    (__attribute__((address_space(3))) u32*)(lp), 16, 0, 0)

// ---------------------------------------------------------------------------
// fp32 -> bf16 bulk convert, ALL five weight tensors in one launch.
__global__ __launch_bounds__(256) void conv_all(
    const float* __restrict__ s0, u16* __restrict__ d0,
    const float* __restrict__ s1, u16* __restrict__ d1,
    const float* __restrict__ s2, u16* __restrict__ d2,
    const float* __restrict__ s3, u16* __restrict__ d3,
    const float* __restrict__ s4, u16* __restrict__ d4) {
  const float* s; u16* d; int local;
  int blk = blockIdx.x;
  if (blk < 16384) {
    int p = blk >> 12; local = blk & 4095;
    s = (p == 0) ? s0 : (p == 1) ? s1 : (p == 2) ? s2 : s3;
    d = (p == 0) ? d0 : (p == 1) ? d1 : (p == 2) ? d2 : d3;
  } else {
    s = s4; d = d4; local = blk - 16384;
  }
  int i = local * 256 + threadIdx.x;
  float4 v = ((const float4*)s)[i];
  ushort4 o;
  o.x = f2bf(v.x); o.y = f2bf(v.y); o.z = f2bf(v.z); o.w = f2bf(v.w);
  ((ushort4*)d)[i] = o;
}

// cond_e gather + fused bias vectors (bih+bhh) + zero barrier state (512 words)
__global__ __launch_bounds__(256) void prep_small(
    const int* __restrict__ cond, const float* __restrict__ emb_cond,
    const float* __restrict__ bihN, const float* __restrict__ bhhN,
    const float* __restrict__ bihD, const float* __restrict__ bhhD,
    float* __restrict__ ce, float* __restrict__ biasN, float* __restrict__ biasD,
    u32* __restrict__ bar) {
  int tid = blockIdx.x * 256 + threadIdx.x;
  if (tid < 512) {
    int b = tid >> 3, j = tid & 7;
    ce[tid] = emb_cond[cond[b] * 8 + j];
  }
  int i = tid - 512;
  if (i >= 0 && i < 4096) {
    biasN[i] = bihN[i] + bhhN[i];
    biasD[i] = bihD[i] + bhhD[i];
  }
  int k = tid - 4608;
  if (k >= 0 && k < 512) bar[k] = 0;
}

// encoder h0 = [zeros(B,1016), cond_e] -> bf16 into hbuf[0]
__global__ __launch_bounds__(256) void init_enc(const float* __restrict__ ce,
                                                u16* __restrict__ hb0) {
  int tid = blockIdx.x * 256 + threadIdx.x;   // 64*1024
  int b = tid >> 10, col = tid & 1023;
  float v = (col >= 1016) ? ce[b * 8 + (col - 1016)] : 0.f;
  hb0[tid] = f2bf(v);
}

// embedding row gather -> bf16, X[t*64+b][1024]
__global__ __launch_bounds__(256) void gather_kernel(const float* __restrict__ emb,
                                                     const int* __restrict__ words,
                                                     u16* __restrict__ X, int dec) {
  int r = blockIdx.x;                    // r = t*64 + b
  int t = r >> 6, b = r & 63;
  int tok = dec ? ((t == 0) ? 0 : words[b * 64 + t - 1]) : words[b * 64 + t];
  float4 v = ((const float4*)(emb + (size_t)tok * 1024))[threadIdx.x];
  ushort4 o;
  o.x = f2bf(v.x); o.y = f2bf(v.y); o.z = f2bf(v.z); o.w = f2bf(v.w);
  ((ushort4*)(X + (size_t)r * 1024))[threadIdx.x] = o;
}

// ---------------------------------------------------------------------------
// C = A(MxK) * B(NxK)^T + bias, bf16 in, fp32 out. 256x128 tile, BK=32,
// 512 threads = 8 waves (4m x 2n). DOUBLE-BUFFERED LDS (T3 minimum-2-phase):
// issue next K-step's global_load_lds BEFORE current step's ds_read+MFMA;
// one __syncthreads (= vmcnt(0)+barrier) per K-step. Staging overlaps MFMA.
// MODE 0 (Xp GEMMs): n-fast + bijective XCD swizzle.
// MODE 1 (logits): per-XCD n-partition + NT C stores.
template <int MODE>
__global__ __launch_bounds__(512) void gemm_bt_kernel(
    const u16* __restrict__ A, const u16* __restrict__ B,
    float* __restrict__ C, const float* __restrict__ bias, int N, int K) {
  __shared__ u16 lA[2][256 * 32];   // 2 x 16KB
  __shared__ u16 lB[2][128 * 32];   // 2 x 8KB
  const int tid = threadIdx.x;
  const int lane = tid & 63;
  const int wid = tid >> 6;      // 0..7

  int tile_m, tile_n;
  if (MODE == 0) {
    const int nn = N >> 7;
    const int nwg = gridDim.x;
    const int orig = blockIdx.x;
    const int wgid = (orig & 7) * (nwg >> 3) + (orig >> 3);
    tile_m = (wgid / nn) * 256;
    tile_n = (wgid % nn) * 128;
  } else {
    const int i = blockIdx.x;        // 0..4095
    const int x = i & 7;             // XCD id
    const int k = i >> 3;
    const int mg = k >> 6;
    const int r  = k & 63;
    const int kn = r >> 1;
    const int mi = r & 1;
    const int tn = kn * 8 + x;
    if (tn >= 250) return;           // dummy (whole WG exits: no barrier issue)
    tile_m = (mg * 2 + mi) * 256;
    tile_n = tn * 128;
  }
  const int wm = wid >> 1, wn = wid & 1;

  const int ldr = lane >> 2;
  const int lko = (lane & 3) * 8;
  const int l15 = lane & 15;
  const int g4 = lane >> 4;

  const size_t aBase = (size_t)tile_m * K;
  const size_t bBase = (size_t)tile_n * K;

  // stage K-step k0 into buffer buf (A: 2 chunks/wave, B: 1 chunk/wave)
  auto stage = [&](int buf, int k0) {
#pragma unroll
    for (int q = 0; q < 2; ++q) {
      int chk = wid * 2 + q;
      int row = chk * 16 + ldr;
      GLD16(A + aBase + (size_t)row * K + k0 + lko, &lA[buf][chk * 512]);
    }
    int row = wid * 16 + ldr;
    GLD16(B + bBase + (size_t)row * K + k0 + lko, &lB[buf][wid * 512]);
  };

  f32x4 acc[4][4];
#pragma unroll
  for (int i = 0; i < 4; ++i)
#pragma unroll
    for (int j = 0; j < 4; ++j) acc[i][j] = (f32x4)0.f;

  stage(0, 0);
  __syncthreads();                    // drain prologue stage

  const int NIT = K >> 5;
  for (int it = 0; it < NIT; ++it) {
    const int cur = it & 1;
    if (it + 1 < NIT) stage(cur ^ 1, (it + 1) * 32);   // prefetch next step
    short8 af[4], bf[4];
#pragma unroll
    for (int i = 0; i < 4; ++i)
      af[i] = *(const short8*)&lA[cur][(wm * 64 + i * 16 + l15) * 32 + g4 * 8];
#pragma unroll
    for (int j = 0; j < 4; ++j)
      bf[j] = *(const short8*)&lB[cur][(wn * 64 + j * 16 + l15) * 32 + g4 * 8];
#pragma unroll
    for (int i = 0; i < 4; ++i)
#pragma unroll
      for (int j = 0; j < 4; ++j)
        acc[i][j] = __builtin_amdgcn_mfma_f32_16x16x32_bf16(af[i], bf[j], acc[i][j], 0, 0, 0);
    __syncthreads();                  // vmcnt(0)+barrier: next buffer ready
  }

#pragma unroll
  for (int i = 0; i < 4; ++i) {
    int row0 = tile_m + wm * 64 + i * 16 + (g4 << 2);
#pragma unroll
    for (int j = 0; j < 4; ++j) {
      int col = tile_n + wn * 64 + j * 16 + l15;
      float bv = bias[col];
#pragma unroll
      for (int e = 0; e < 4; ++e) {
        size_t o = (size_t)(row0 + e) * (size_t)N + col;
        float v = acc[i][j][e] + bv;
        if (MODE == 1) __builtin_nontemporal_store(v, &C[o]);
        else           C[o] = v;
      }
    }
  }
}

// ---------------------------------------------------------------------------
// CLUSTERED PERSISTENT LSTM (r14-proven skeleton). 4 independent clusters x
// 16 batch rows; 32 WGs/cluster, WG owns 32 h-cols (full K). Whh slice in
// 128 VGPRs/wave for all 64 steps. Agent-atomic h stores (write-through) +
// agent-atomic staging loads. FLAT fence-free cluster barrier: vmcnt(0)
// orders h stores, RELAXED arrive store, then EVERY WG's tid<32 polls the
// cluster's 32 arrive words directly (no leader/flag hop — saves one
// coherence-point round trip per step vs r14).
__global__ __launch_bounds__(512, 1) void lstm_cluster(
    const u16* __restrict__ Whh, const float* __restrict__ Xp,
    u16* __restrict__ hbuf,        // [2][64][1024] bf16 double buffer
    u16* __restrict__ hs_out,      // decoder: [b*64+t][1024] bf16, else null
    float* __restrict__ hT_out,    // encoder: [64][1024] fp32, else null
    u32* arrive) {                 // arrive[128]
  __shared__ __align__(16) char smemA[32768];   // 16 rows x 2048B, swizzled
  __shared__ float lg[8][16][16];               // [wave][batchrow][col16]
  const int tid = threadIdx.x;      // 0..511
  const int lane = tid & 63;
  const int v = tid >> 6;           // wave 0..7
  const int gate = v >> 1;
  const int ch = v & 1;             // col-half of the WG's 32 cols
  const int wgi = blockIdx.x;       // 0..127
  const int c = wgi >> 5;           // cluster 0..3 (owns batch rows c*16..+16)
  const int j = wgi & 31;           // WG within cluster (owns cols j*32..+32)
  const int b0 = c * 16, col0 = j * 32;
  const int l15 = lane & 15, g4 = lane >> 4;

  // Whh fragments: loaded ONCE, live across all 64 steps (128 VGPRs)
  short8 breg[32];
  {
    const u16* Brow = Whh + (size_t)(gate * 1024 + col0 + ch * 16 + l15) * 1024
                          + g4 * 8;
#pragma unroll
    for (int kk = 0; kk < 32; ++kk)
      breg[kk] = *(const short8*)(Brow + kk * 32);
  }

  // cell mapping: 512 threads = 16 rows x 32 cols
  const int crow = tid >> 5, colw = tid & 31;
  const int bg = b0 + crow, cgl = col0 + colw;
  const int ch2 = colw >> 4, cw = colw & 15;
  float creg = 0.f;

  for (int t = 0; t < 64; ++t) {
    const char* rbase = (const char*)(hbuf + (size_t)(t & 1) * 65536)
                      + (size_t)b0 * 2048;
    u32* wb32 = (u32*)(hbuf + (size_t)((t + 1) & 1) * 65536);

    // ---- Xp prefetch (independent; issues first)
    size_t xrow = (size_t)(t * 64 + bg) * 4096 + cgl;
    float xg0 = __builtin_nontemporal_load(&Xp[xrow]);
    float xg1 = __builtin_nontemporal_load(&Xp[xrow + 1024]);
    float xg2 = __builtin_nontemporal_load(&Xp[xrow + 2048]);
    float xg3 = __builtin_nontemporal_load(&Xp[xrow + 3072]);

    // ---- stage h slab (16 rows x 1024 cols) -> swizzled LDS, atomic loads
#pragma unroll
    for (int q = 0; q < 4; ++q) {
      int g = q * 512 + tid;              // 16B chunk id 0..2047
      int row = g >> 7;                   // 0..15
      int cb = (g & 127) * 16;            // byte col in row
      const u64* src = (const u64*)(rbase + (size_t)row * 2048 + cb);
      u64 lo = __hip_atomic_load(src,     __ATOMIC_RELAXED, __HIP_MEMORY_SCOPE_AGENT);
      u64 hi = __hip_atomic_load(src + 1, __ATOMIC_RELAXED, __HIP_MEMORY_SCOPE_AGENT);
      u64* d = (u64*)(smemA + row * 2048 + (cb ^ ((row & 7) << 4)));
      d[0] = lo; d[1] = hi;
    }
    __syncthreads();

    // ---- 32 MFMAs/wave (4 chains), A from swizzled LDS, B from regs
    f32x4 a4[4] = {(f32x4)0.f, (f32x4)0.f, (f32x4)0.f, (f32x4)0.f};
#pragma unroll
    for (int kk = 0; kk < 32; ++kk) {
      int cb2 = kk * 64 + g4 * 16;
      const short8 a = *(const short8*)(smemA + l15 * 2048 + (cb2 ^ ((l15 & 7) << 4)));
      a4[kk & 3] = __builtin_amdgcn_mfma_f32_16x16x32_bf16(a, breg[kk], a4[kk & 3], 0, 0, 0);
    }
    f32x4 asum = a4[0] + a4[1] + a4[2] + a4[3];
    {
      int m = g4 * 4;
#pragma unroll
      for (int e = 0; e < 4; ++e) lg[v][m + e][l15] = asum[e];
    }
    __syncthreads();

    // ---- cell update: 1 cell per thread
    {
      float gi = lg[0 + ch2][crow][cw] + xg0;
      float gf = lg[2 + ch2][crow][cw] + xg1;
      float gg = lg[4 + ch2][crow][cw] + xg2;
      float go = lg[6 + ch2][crow][cw] + xg3;
      float si = 1.f / (1.f + __expf(-gi));
      float sf = 1.f / (1.f + __expf(-gf));
      float so = 1.f / (1.f + __expf(-go));
      float tg = tanhf(gg);
      float cn = sf * creg + si * tg;
      float hn = so * tanhf(cn);
      creg = cn;
      u16 h16 = f2bf(hn);
      u32 mine = h16;
      u32 other = (u32)__shfl_xor((int)mine, 1);
      if (!(colw & 1)) {
        u32 pk = mine | (other << 16);
        __hip_atomic_store(wb32 + (((size_t)bg * 1024 + cgl) >> 1), pk,
                           __ATOMIC_RELAXED, __HIP_MEMORY_SCOPE_AGENT);
      }
      if (hs_out) hs_out[((size_t)bg * 64 + t) * 1024 + cgl] = h16;  // cross-kernel
      if (hT_out && t == 63) hT_out[bg * 1024 + cgl] = hn;           // cross-kernel
    }

    // ---- flat fence-free cluster barrier (32 WGs; skip after last step)
    if (t != 63) {
      u32 want = (u32)(t + 1);
      asm volatile("s_waitcnt vmcnt(0)" ::: "memory");   // h stores at coherence pt
      __syncthreads();
      if (tid == 0)
        __hip_atomic_store(&arrive[wgi], want, __ATOMIC_RELAXED,
                           __HIP_MEMORY_SCOPE_AGENT);
      if (tid < 32) {
        int guard = 0;
        while (__hip_atomic_load(&arrive[c * 32 + tid], __ATOMIC_RELAXED,
                                 __HIP_MEMORY_SCOPE_AGENT) < want) {
          __builtin_amdgcn_s_sleep(2);
          if (++guard > (1 << 20)) break;   // safety valve
        }
      }
      __syncthreads();
    }
  }
}

// ---------------------------------------------------------------------------
// mean/logvar/latent + hd0 = [latent|cond_e] @ W_st^T + b_st -> bf16 h0.
__global__ __launch_bounds__(256) void latent_hd0_kernel(
    const float* hT, const float* Wm, const float* bm,
    const float* Wl, const float* bl, const float* Wst, const float* bst,
    const float* eps, const float* ce, u16* hb0) {
  __shared__ float red[64][4];
  __shared__ float ml[64];
  __shared__ float lat[40];
  int b = blockIdx.x;
  int tid = threadIdx.x;
  int o = tid >> 2, p = tid & 3;
  const float* w = (o < 32) ? (Wm + (size_t)o * 1024) : (Wl + (size_t)(o - 32) * 1024);
  const float* h = hT + (size_t)b * 1024;
  float s = 0.f;
  for (int k = p * 256; k < p * 256 + 256; ++k) s += h[k] * w[k];
  red[o][p] = s;
  __syncthreads();
  if (tid < 64) {
    float v = red[tid][0] + red[tid][1] + red[tid][2] + red[tid][3];
    v += (tid < 32) ? bm[tid] : bl[tid - 32];
    ml[tid] = v;
  }
  __syncthreads();
  if (tid < 32) lat[tid] = eps[b * 32 + tid] * __expf(0.5f * ml[32 + tid]) + ml[tid];
  if (tid >= 32 && tid < 40) lat[tid] = ce[b * 8 + (tid - 32)];
  __syncthreads();
  for (int hc = tid; hc < 1024; hc += 256) {
    float s2 = bst[hc];
    const float* wr = Wst + (size_t)hc * 40;
#pragma unroll
    for (int j = 0; j < 40; ++j) s2 += lat[j] * wr[j];
    hb0[b * 1024 + hc] = f2bf(s2);
  }
}

// ---------------------------------------------------------------------------
extern "C" void kernel_launch(void* const* d_in, const int* in_sizes, int n_in,
                              void* d_out, int out_size, void* d_ws, size_t ws_size,
                              hipStream_t stream) {
  const int*   input_word = (const int*)d_in[0];
  const int*   cond       = (const int*)d_in[1];
  const float* emb_N      = (const float*)d_in[2];
  const float* Wih_N      = (const float*)d_in[3];
  const float* Whh_N      = (const float*)d_in[4];
  const float* bih_N      = (const float*)d_in[5];
  const float* bhh_N      = (const float*)d_in[6];
  const float* emb_D      = (const float*)d_in[7];
  const float* Wih_D      = (const float*)d_in[8];
  const float* Whh_D      = (const float*)d_in[9];
  const float* bih_D      = (const float*)d_in[10];
  const float* bhh_D      = (const float*)d_in[11];
  const float* emb_cond   = (const float*)d_in[12];
  const float* W_mean     = (const float*)d_in[13];
  const float* b_mean     = (const float*)d_in[14];
  const float* W_logvar   = (const float*)d_in[15];
  const float* b_logvar   = (const float*)d_in[16];
  const float* W_st       = (const float*)d_in[17];
  const float* b_st       = (const float*)d_in[18];
  const float* W_out      = (const float*)d_in[19];
  const float* b_out      = (const float*)d_in[20];
  const float* eps        = (const float*)d_in[21];
  float* out = (float*)d_out;

  char* ws = (char*)d_ws;
  size_t off = 0;
  auto alloc = [&](size_t b) { size_t p = off; off += (b + 255) & ~(size_t)255; return p; };
  u16*   wihN = (u16*)(ws + alloc(4096ull * 1024 * 2));
  u16*   whhN = (u16*)(ws + alloc(4096ull * 1024 * 2));
  u16*   wihD = (u16*)(ws + alloc(4096ull * 1024 * 2));
  u16*   whhD = (u16*)(ws + alloc(4096ull * 1024 * 2));
  u16*   wout = (u16*)(ws + alloc(32000ull * 1024 * 2));
  u16*   Xe   = (u16*)(ws + alloc(4096ull * 1024 * 2));
  u16*   Xd   = (u16*)(ws + alloc(4096ull * 1024 * 2));
  float* Xp   = (float*)(ws + alloc(4096ull * 4096 * 4));   // enc then dec
  u16*   hsd  = (u16*)(ws + alloc(4096ull * 1024 * 2));     // [b*64+t][1024]
  u16*   hb   = (u16*)(ws + alloc(2ull * 64 * 1024 * 2));   // bf16 h dbuf
  float* hf   = (float*)(ws + alloc(64ull * 1024 * 4));     // fp32 h_T (encoder)
  float* biasN = (float*)(ws + alloc(4096 * 4));
  float* biasD = (float*)(ws + alloc(4096 * 4));
  float* ce    = (float*)(ws + alloc(64 * 8 * 4));
  u32*   bar   = (u32*)(ws + alloc(2048));
  // bar: enc arrive bar[0..127], dec arrive bar[256..383]
  if (off > ws_size) return;

  conv_all<<<48384, 256, 0, stream>>>(Wih_N, wihN, Whh_N, whhN,
                                      Wih_D, wihD, Whh_D, whhD, W_out, wout);
  prep_small<<<20, 256, 0, stream>>>(cond, emb_cond, bih_N, bhh_N, bih_D, bhh_D,
                                     ce, biasN, biasD, bar);
  gather_kernel<<<4096, 256, 0, stream>>>(emb_N, input_word, Xe, 0);
  gather_kernel<<<4096, 256, 0, stream>>>(emb_D, input_word, Xd, 1);
  init_enc<<<256, 256, 0, stream>>>(ce, hb);

  // encoder precompute + clustered persistent recurrence
  gemm_bt_kernel<0><<<512, 512, 0, stream>>>(Xe, wihN, Xp, biasN, 4096, 1024);
  lstm_cluster<<<128, 512, 0, stream>>>(whhN, Xp, hb, nullptr, hf, bar + 0);
  // latent + decoder h0 (writes hb[0]; decoder c0=0 is in-register)
  latent_hd0_kernel<<<64, 256, 0, stream>>>(hf, W_mean, b_mean, W_logvar, b_logvar,
                                            W_st, b_st, eps, ce, hb);
  // decoder precompute + clustered persistent recurrence
  gemm_bt_kernel<0><<<512, 512, 0, stream>>>(Xd, wihD, Xp, biasD, 4096, 1024);
  lstm_cluster<<<128, 512, 0, stream>>>(whhD, Xp, hb, hsd, nullptr, bar + 256);
  // logits[b][t][:] = hsd[b*64+t] @ W_out^T + b_out (per-XCD n-partition, NT)
  gemm_bt_kernel<1><<<4096, 512, 0, stream>>>(hsd, wout, out, b_out, 32000, 1024);
}

// Round 16
// 1011.356 us; speedup vs baseline: 5.3417x; 1.0540x over previous
//
#include <hip/hip_runtime.h>
#include <hip/hip_bf16.h>

typedef unsigned short u16;
typedef unsigned int   u32;
typedef unsigned long long u64;
typedef __attribute__((ext_vector_type(8))) short short8;   // 8 x bf16 (4 VGPRs)
typedef __attribute__((ext_vector_type(4))) float f32x4;

#define DEVINL static __device__ __forceinline__

// round-to-nearest-even f32 -> bf16
DEVINL u16 f2bf(float x) {
  u32 u = __float_as_uint(x);
  u32 r = (u + 0x7fffu + ((u >> 16) & 1u)) >> 16;
  return (u16)r;
}

// async global->LDS, 16B per lane. LDS dest = uniform base + lane*16.
#define GLD16(gp, lp) __builtin_amdgcn_global_load_lds(                     \
    (const __attribute__((address_space(1))) u32*)(gp),                     \
    (__attribute__((address_space(3))) u32*)(lp), 16, 0, 0)

// ---------------------------------------------------------------------------
// fp32 -> bf16 bulk convert, ALL five weight tensors in one launch.
__global__ __launch_bounds__(256) void conv_all(
    const float* __restrict__ s0, u16* __restrict__ d0,
    const float* __restrict__ s1, u16* __restrict__ d1,
    const float* __restrict__ s2, u16* __restrict__ d2,
    const float* __restrict__ s3, u16* __restrict__ d3,
    const float* __restrict__ s4, u16* __restrict__ d4) {
  const float* s; u16* d; int local;
  int blk = blockIdx.x;
  if (blk < 16384) {
    int p = blk >> 12; local = blk & 4095;
    s = (p == 0) ? s0 : (p == 1) ? s1 : (p == 2) ? s2 : s3;
    d = (p == 0) ? d0 : (p == 1) ? d1 : (p == 2) ? d2 : d3;
  } else {
    s = s4; d = d4; local = blk - 16384;
  }
  int i = local * 256 + threadIdx.x;
  float4 v = ((const float4*)s)[i];
  ushort4 o;
  o.x = f2bf(v.x); o.y = f2bf(v.y); o.z = f2bf(v.z); o.w = f2bf(v.w);
  ((ushort4*)d)[i] = o;
}

// cond_e gather + fused bias vectors (bih+bhh) + zero barrier state (512 words)
__global__ __launch_bounds__(256) void prep_small(
    const int* __restrict__ cond, const float* __restrict__ emb_cond,
    const float* __restrict__ bihN, const float* __restrict__ bhhN,
    const float* __restrict__ bihD, const float* __restrict__ bhhD,
    float* __restrict__ ce, float* __restrict__ biasN, float* __restrict__ biasD,
    u32* __restrict__ bar) {
  int tid = blockIdx.x * 256 + threadIdx.x;
  if (tid < 512) {
    int b = tid >> 3, j = tid & 7;
    ce[tid] = emb_cond[cond[b] * 8 + j];
  }
  int i = tid - 512;
  if (i >= 0 && i < 4096) {
    biasN[i] = bihN[i] + bhhN[i];
    biasD[i] = bihD[i] + bhhD[i];
  }
  int k = tid - 4608;
  if (k >= 0 && k < 512) bar[k] = 0;
}

// encoder h0 = [zeros(B,1016), cond_e] -> bf16 into hbuf[0]
__global__ __launch_bounds__(256) void init_enc(const float* __restrict__ ce,
                                                u16* __restrict__ hb0) {
  int tid = blockIdx.x * 256 + threadIdx.x;   // 64*1024
  int b = tid >> 10, col = tid & 1023;
  float v = (col >= 1016) ? ce[b * 8 + (col - 1016)] : 0.f;
  hb0[tid] = f2bf(v);
}

// embedding row gather -> bf16, X[t*64+b][1024]
__global__ __launch_bounds__(256) void gather_kernel(const float* __restrict__ emb,
                                                     const int* __restrict__ words,
                                                     u16* __restrict__ X, int dec) {
  int r = blockIdx.x;                    // r = t*64 + b
  int t = r >> 6, b = r & 63;
  int tok = dec ? ((t == 0) ? 0 : words[b * 64 + t - 1]) : words[b * 64 + t];
  float4 v = ((const float4*)(emb + (size_t)tok * 1024))[threadIdx.x];
  ushort4 o;
  o.x = f2bf(v.x); o.y = f2bf(v.y); o.z = f2bf(v.z); o.w = f2bf(v.w);
  ((ushort4*)(X + (size_t)r * 1024))[threadIdx.x] = o;
}

// ---------------------------------------------------------------------------
// GEMM body, MODE-0 style (n-fast + bijective XCD swizzle), 256x128 tile,
// BK=32, 512 threads = 8 waves (4m x 2n), double-buffered LDS (48KB).
// smemc layout: [0,32K) = lA[2], [32K,48K) = lB[2].
DEVINL void gemm0_body(char* smemc, int bid, int nwg,
                       const u16* __restrict__ A, const u16* __restrict__ B,
                       float* __restrict__ C, const float* __restrict__ bias,
                       int N, int K) {
  u16 (*lA)[256 * 32] = (u16(*)[256 * 32])smemc;
  u16 (*lB)[128 * 32] = (u16(*)[128 * 32])(smemc + 32768);
  const int tid = threadIdx.x;
  const int lane = tid & 63;
  const int wid = tid >> 6;

  const int nn = N >> 7;
  const int wgid = (bid & 7) * (nwg >> 3) + (bid >> 3);
  const int tile_m = (wgid / nn) * 256;
  const int tile_n = (wgid % nn) * 128;
  const int wm = wid >> 1, wn = wid & 1;

  const int ldr = lane >> 2;
  const int lko = (lane & 3) * 8;
  const int l15 = lane & 15;
  const int g4 = lane >> 4;

  const size_t aBase = (size_t)tile_m * K;
  const size_t bBase = (size_t)tile_n * K;

  auto stage = [&](int buf, int k0) {
#pragma unroll
    for (int q = 0; q < 2; ++q) {
      int chk = wid * 2 + q;
      int row = chk * 16 + ldr;
      GLD16(A + aBase + (size_t)row * K + k0 + lko, &lA[buf][chk * 512]);
    }
    int row = wid * 16 + ldr;
    GLD16(B + bBase + (size_t)row * K + k0 + lko, &lB[buf][wid * 512]);
  };

  f32x4 acc[4][4];
#pragma unroll
  for (int i = 0; i < 4; ++i)
#pragma unroll
    for (int j = 0; j < 4; ++j) acc[i][j] = (f32x4)0.f;

  stage(0, 0);
  __syncthreads();

  const int NIT = K >> 5;
  for (int it = 0; it < NIT; ++it) {
    const int cur = it & 1;
    if (it + 1 < NIT) stage(cur ^ 1, (it + 1) * 32);
    short8 af[4], bf[4];
#pragma unroll
    for (int i = 0; i < 4; ++i)
      af[i] = *(const short8*)&lA[cur][(wm * 64 + i * 16 + l15) * 32 + g4 * 8];
#pragma unroll
    for (int j = 0; j < 4; ++j)
      bf[j] = *(const short8*)&lB[cur][(wn * 64 + j * 16 + l15) * 32 + g4 * 8];
#pragma unroll
    for (int i = 0; i < 4; ++i)
#pragma unroll
      for (int j = 0; j < 4; ++j)
        acc[i][j] = __builtin_amdgcn_mfma_f32_16x16x32_bf16(af[i], bf[j], acc[i][j], 0, 0, 0);
    __syncthreads();
  }

#pragma unroll
  for (int i = 0; i < 4; ++i) {
    int row0 = tile_m + wm * 64 + i * 16 + (g4 << 2);
#pragma unroll
    for (int j = 0; j < 4; ++j) {
      int col = tile_n + wn * 64 + j * 16 + l15;
      float bv = bias[col];
#pragma unroll
      for (int e = 0; e < 4; ++e)
        C[(size_t)(row0 + e) * (size_t)N + col] = acc[i][j][e] + bv;
    }
  }
}

// ---------------------------------------------------------------------------
// CLUSTERED PERSISTENT LSTM body (r15-proven skeleton + Xp prefetch hoist:
// next-step Xp gate loads are issued right after the h-store and drained by
// the same vmcnt(0) — their HBM latency hides under the store drain + poll).
// smemc: [0,32K) = swizzled A slab, [32K,40K) = lg exchange.
DEVINL void lstm_body(char* smemc, const u16* __restrict__ Whh,
                      const float* __restrict__ Xp, u16* __restrict__ hbuf,
                      u16* __restrict__ hs_out, float* __restrict__ hT_out,
                      u32* arrive, int wgi) {
  char* smemA = smemc;
  float (*lg)[16][16] = (float(*)[16][16])(smemc + 32768);
  const int tid = threadIdx.x;      // 0..511
  const int lane = tid & 63;
  const int v = tid >> 6;           // wave 0..7
  const int gate = v >> 1;
  const int ch = v & 1;             // col-half of the WG's 32 cols
  const int c = wgi >> 5;           // cluster 0..3 (batch rows c*16..+16)
  const int j = wgi & 31;           // WG in cluster (cols j*32..+32)
  const int b0 = c * 16, col0 = j * 32;
  const int l15 = lane & 15, g4 = lane >> 4;

  // Whh fragments: loaded ONCE, live across all 64 steps (128 VGPRs)
  short8 breg[32];
  {
    const u16* Brow = Whh + (size_t)(gate * 1024 + col0 + ch * 16 + l15) * 1024
                          + g4 * 8;
#pragma unroll
    for (int kk = 0; kk < 32; ++kk)
      breg[kk] = *(const short8*)(Brow + kk * 32);
  }

  // cell mapping: 512 threads = 16 rows x 32 cols
  const int crow = tid >> 5, colw = tid & 31;
  const int bg = b0 + crow, cgl = col0 + colw;
  const int ch2 = colw >> 4, cw = colw & 15;
  float creg = 0.f;

  // prologue: Xp prefetch for t=0
  float xg0, xg1, xg2, xg3;
  {
    size_t xrow = (size_t)bg * 4096 + cgl;
    xg0 = __builtin_nontemporal_load(&Xp[xrow]);
    xg1 = __builtin_nontemporal_load(&Xp[xrow + 1024]);
    xg2 = __builtin_nontemporal_load(&Xp[xrow + 2048]);
    xg3 = __builtin_nontemporal_load(&Xp[xrow + 3072]);
  }

  for (int t = 0; t < 64; ++t) {
    const char* rbase = (const char*)(hbuf + (size_t)(t & 1) * 65536)
                      + (size_t)b0 * 2048;
    u32* wb32 = (u32*)(hbuf + (size_t)((t + 1) & 1) * 65536);

    // ---- stage h slab (16 rows x 1024 cols) -> swizzled LDS, atomic loads
#pragma unroll
    for (int q = 0; q < 4; ++q) {
      int g = q * 512 + tid;              // 16B chunk id 0..2047
      int row = g >> 7;                   // 0..15
      int cb = (g & 127) * 16;            // byte col in row
      const u64* src = (const u64*)(rbase + (size_t)row * 2048 + cb);
      u64 lo = __hip_atomic_load(src,     __ATOMIC_RELAXED, __HIP_MEMORY_SCOPE_AGENT);
      u64 hi = __hip_atomic_load(src + 1, __ATOMIC_RELAXED, __HIP_MEMORY_SCOPE_AGENT);
      u64* d = (u64*)(smemA + row * 2048 + (cb ^ ((row & 7) << 4)));
      d[0] = lo; d[1] = hi;
    }
    __syncthreads();

    // ---- 32 MFMAs/wave (4 chains), A from swizzled LDS, B from regs
    f32x4 a4[4] = {(f32x4)0.f, (f32x4)0.f, (f32x4)0.f, (f32x4)0.f};
#pragma unroll
    for (int kk = 0; kk < 32; ++kk) {
      int cb2 = kk * 64 + g4 * 16;
      const short8 a = *(const short8*)(smemA + l15 * 2048 + (cb2 ^ ((l15 & 7) << 4)));
      a4[kk & 3] = __builtin_amdgcn_mfma_f32_16x16x32_bf16(a, breg[kk], a4[kk & 3], 0, 0, 0);
    }
    f32x4 asum = a4[0] + a4[1] + a4[2] + a4[3];
    {
      int m = g4 * 4;
#pragma unroll
      for (int e = 0; e < 4; ++e) lg[v][m + e][l15] = asum[e];
    }
    __syncthreads();

    // ---- cell update: 1 cell per thread (uses prefetched xg)
    {
      float gi = lg[0 + ch2][crow][cw] + xg0;
      float gf = lg[2 + ch2][crow][cw] + xg1;
      float gg = lg[4 + ch2][crow][cw] + xg2;
      float go = lg[6 + ch2][crow][cw] + xg3;
      float si = 1.f / (1.f + __expf(-gi));
      float sf = 1.f / (1.f + __expf(-gf));
      float so = 1.f / (1.f + __expf(-go));
      float tg = tanhf(gg);
      float cn = sf * creg + si * tg;
      float hn = so * tanhf(cn);
      creg = cn;
      u16 h16 = f2bf(hn);
      u32 mine = h16;
      u32 other = (u32)__shfl_xor((int)mine, 1);
      if (!(colw & 1)) {
        u32 pk = mine | (other << 16);
        __hip_atomic_store(wb32 + (((size_t)bg * 1024 + cgl) >> 1), pk,
                           __ATOMIC_RELAXED, __HIP_MEMORY_SCOPE_AGENT);
      }
      if (hs_out) hs_out[((size_t)bg * 64 + t) * 1024 + cgl] = h16;  // cross-kernel
      if (hT_out && t == 63) hT_out[bg * 1024 + cgl] = hn;           // cross-kernel
    }

    // ---- prefetch next-step Xp, then flat fence-free cluster barrier
    if (t != 63) {
      {
        size_t xrow = (size_t)((t + 1) * 64 + bg) * 4096 + cgl;
        xg0 = __builtin_nontemporal_load(&Xp[xrow]);
        xg1 = __builtin_nontemporal_load(&Xp[xrow + 1024]);
        xg2 = __builtin_nontemporal_load(&Xp[xrow + 2048]);
        xg3 = __builtin_nontemporal_load(&Xp[xrow + 3072]);
      }
      u32 want = (u32)(t + 1);
      asm volatile("s_waitcnt vmcnt(0)" ::: "memory");   // drains h stores + Xp
      __syncthreads();
      if (tid == 0)
        __hip_atomic_store(&arrive[wgi], want, __ATOMIC_RELAXED,
                           __HIP_MEMORY_SCOPE_AGENT);
      if (tid < 32) {
        int guard = 0;
        while (__hip_atomic_load(&arrive[c * 32 + tid], __ATOMIC_RELAXED,
                                 __HIP_MEMORY_SCOPE_AGENT) < want) {
          __builtin_amdgcn_s_sleep(2);
          if (++guard > (1 << 20)) break;   // safety valve
        }
      }
      __syncthreads();
    }
  }
}

// ---------------------------------------------------------------------------
// Standalone wrappers + fused encoder kernel.
__global__ __launch_bounds__(512, 1) void lstm_cluster(
    const u16* __restrict__ Whh, const float* __restrict__ Xp,
    u16* __restrict__ hbuf, u16* __restrict__ hs_out,
    float* __restrict__ hT_out, u32* arrive) {
  __shared__ __align__(16) char smem[40960];
  lstm_body(smem, Whh, Xp, hbuf, hs_out, hT_out, arrive, blockIdx.x);
}

__global__ __launch_bounds__(512) void gemm_bt0(
    const u16* __restrict__ A, const u16* __restrict__ B,
    float* __restrict__ C, const float* __restrict__ bias, int N, int K) {
  __shared__ __align__(16) char smem[49152];
  gemm0_body(smem, blockIdx.x, gridDim.x, A, B, C, bias, N, K);
}

// Fused: blocks 0..127 = encoder persistent LSTM (dispatched first -> all
// co-resident); blocks 128..639 = decoder-Xp GEMM (independent work, hidden
// under the LSTM's ~230us).
__global__ __launch_bounds__(512, 1) void enc_fused(
    const u16* __restrict__ whhN, const float* __restrict__ XpE,
    u16* __restrict__ hbuf, float* __restrict__ hT_out, u32* arrive,
    const u16* __restrict__ Xd, const u16* __restrict__ wihD,
    float* __restrict__ XpD, const float* __restrict__ biasD) {
  __shared__ __align__(16) char smem[49152];
  if (blockIdx.x < 128)
    lstm_body(smem, whhN, XpE, hbuf, nullptr, hT_out, arrive, blockIdx.x);
  else
    gemm0_body(smem, blockIdx.x - 128, 512, Xd, wihD, XpD, biasD, 4096, 1024);
}

// ---------------------------------------------------------------------------
// Logits GEMM (MODE 1, unchanged from r15): per-XCD n-partition, 2-phase
// dbuf, NT C stores.
__global__ __launch_bounds__(512) void gemm_bt1(
    const u16* __restrict__ A, const u16* __restrict__ B,
    float* __restrict__ C, const float* __restrict__ bias, int N, int K) {
  __shared__ u16 lA[2][256 * 32];
  __shared__ u16 lB[2][128 * 32];
  const int tid = threadIdx.x;
  const int lane = tid & 63;
  const int wid = tid >> 6;

  const int i = blockIdx.x;        // 0..4095
  const int x = i & 7;             // XCD id
  const int k = i >> 3;
  const int mg = k >> 6;
  const int r  = k & 63;
  const int kn = r >> 1;
  const int mi = r & 1;
  const int tn = kn * 8 + x;
  if (tn >= 250) return;           // dummy (whole WG exits)
  const int tile_m = (mg * 2 + mi) * 256;
  const int tile_n = tn * 128;
  const int wm = wid >> 1, wn = wid & 1;

  const int ldr = lane >> 2;
  const int lko = (lane & 3) * 8;
  const int l15 = lane & 15;
  const int g4 = lane >> 4;

  const size_t aBase = (size_t)tile_m * K;
  const size_t bBase = (size_t)tile_n * K;

  auto stage = [&](int buf, int k0) {
#pragma unroll
    for (int q = 0; q < 2; ++q) {
      int chk = wid * 2 + q;
      int row = chk * 16 + ldr;
      GLD16(A + aBase + (size_t)row * K + k0 + lko, &lA[buf][chk * 512]);
    }
    int row = wid * 16 + ldr;
    GLD16(B + bBase + (size_t)row * K + k0 + lko, &lB[buf][wid * 512]);
  };

  f32x4 acc[4][4];
#pragma unroll
  for (int i2 = 0; i2 < 4; ++i2)
#pragma unroll
    for (int j2 = 0; j2 < 4; ++j2) acc[i2][j2] = (f32x4)0.f;

  stage(0, 0);
  __syncthreads();

  const int NIT = K >> 5;
  for (int it = 0; it < NIT; ++it) {
    const int cur = it & 1;
    if (it + 1 < NIT) stage(cur ^ 1, (it + 1) * 32);
    short8 af[4], bf[4];
#pragma unroll
    for (int i2 = 0; i2 < 4; ++i2)
      af[i2] = *(const short8*)&lA[cur][(wm * 64 + i2 * 16 + l15) * 32 + g4 * 8];
#pragma unroll
    for (int j2 = 0; j2 < 4; ++j2)
      bf[j2] = *(const short8*)&lB[cur][(wn * 64 + j2 * 16 + l15) * 32 + g4 * 8];
#pragma unroll
    for (int i2 = 0; i2 < 4; ++i2)
#pragma unroll
      for (int j2 = 0; j2 < 4; ++j2)
        acc[i2][j2] = __builtin_amdgcn_mfma_f32_16x16x32_bf16(af[i2], bf[j2], acc[i2][j2], 0, 0, 0);
    __syncthreads();
  }

#pragma unroll
  for (int i2 = 0; i2 < 4; ++i2) {
    int row0 = tile_m + wm * 64 + i2 * 16 + (g4 << 2);
#pragma unroll
    for (int j2 = 0; j2 < 4; ++j2) {
      int col = tile_n + wn * 64 + j2 * 16 + l15;
      float bv = bias[col];
#pragma unroll
      for (int e = 0; e < 4; ++e) {
        size_t o = (size_t)(row0 + e) * (size_t)N + col;
        __builtin_nontemporal_store(acc[i2][j2][e] + bv, &C[o]);
      }
    }
  }
}

// ---------------------------------------------------------------------------
// mean/logvar/latent + hd0 = [latent|cond_e] @ W_st^T + b_st -> bf16 h0.
__global__ __launch_bounds__(256) void latent_hd0_kernel(
    const float* hT, const float* Wm, const float* bm,
    const float* Wl, const float* bl, const float* Wst, const float* bst,
    const float* eps, const float* ce, u16* hb0) {
  __shared__ float red[64][4];
  __shared__ float ml[64];
  __shared__ float lat[40];
  int b = blockIdx.x;
  int tid = threadIdx.x;
  int o = tid >> 2, p = tid & 3;
  const float* w = (o < 32) ? (Wm + (size_t)o * 1024) : (Wl + (size_t)(o - 32) * 1024);
  const float* h = hT + (size_t)b * 1024;
  float s = 0.f;
  for (int k = p * 256; k < p * 256 + 256; ++k) s += h[k] * w[k];
  red[o][p] = s;
  __syncthreads();
  if (tid < 64) {
    float v = red[tid][0] + red[tid][1] + red[tid][2] + red[tid][3];
    v += (tid < 32) ? bm[tid] : bl[tid - 32];
    ml[tid] = v;
  }
  __syncthreads();
  if (tid < 32) lat[tid] = eps[b * 32 + tid] * __expf(0.5f * ml[32 + tid]) + ml[tid];
  if (tid >= 32 && tid < 40) lat[tid] = ce[b * 8 + (tid - 32)];
  __syncthreads();
  for (int hc = tid; hc < 1024; hc += 256) {
    float s2 = bst[hc];
    const float* wr = Wst + (size_t)hc * 40;
#pragma unroll
    for (int j = 0; j < 40; ++j) s2 += lat[j] * wr[j];
    hb0[b * 1024 + hc] = f2bf(s2);
  }
}

// ---------------------------------------------------------------------------
extern "C" void kernel_launch(void* const* d_in, const int* in_sizes, int n_in,
                              void* d_out, int out_size, void* d_ws, size_t ws_size,
                              hipStream_t stream) {
  const int*   input_word = (const int*)d_in[0];
  const int*   cond       = (const int*)d_in[1];
  const float* emb_N      = (const float*)d_in[2];
  const float* Wih_N      = (const float*)d_in[3];
  const float* Whh_N      = (const float*)d_in[4];
  const float* bih_N      = (const float*)d_in[5];
  const float* bhh_N      = (const float*)d_in[6];
  const float* emb_D      = (const float*)d_in[7];
  const float* Wih_D      = (const float*)d_in[8];
  const float* Whh_D      = (const float*)d_in[9];
  const float* bih_D      = (const float*)d_in[10];
  const float* bhh_D      = (const float*)d_in[11];
  const float* emb_cond   = (const float*)d_in[12];
  const float* W_mean     = (const float*)d_in[13];
  const float* b_mean     = (const float*)d_in[14];
  const float* W_logvar   = (const float*)d_in[15];
  const float* b_logvar   = (const float*)d_in[16];
  const float* W_st       = (const float*)d_in[17];
  const float* b_st       = (const float*)d_in[18];
  const float* W_out      = (const float*)d_in[19];
  const float* b_out      = (const float*)d_in[20];
  const float* eps        = (const float*)d_in[21];
  float* out = (float*)d_out;

  char* ws = (char*)d_ws;
  size_t off = 0;
  auto alloc = [&](size_t b) { size_t p = off; off += (b + 255) & ~(size_t)255; return p; };
  u16*   wihN = (u16*)(ws + alloc(4096ull * 1024 * 2));
  u16*   whhN = (u16*)(ws + alloc(4096ull * 1024 * 2));
  u16*   wihD = (u16*)(ws + alloc(4096ull * 1024 * 2));
  u16*   whhD = (u16*)(ws + alloc(4096ull * 1024 * 2));
  u16*   wout = (u16*)(ws + alloc(32000ull * 1024 * 2));
  u16*   Xe   = (u16*)(ws + alloc(4096ull * 1024 * 2));
  u16*   Xd   = (u16*)(ws + alloc(4096ull * 1024 * 2));
  float* Xp   = (float*)(ws + alloc(4096ull * 4096 * 4));   // enc (and dec fallback)
  u16*   hsd  = (u16*)(ws + alloc(4096ull * 1024 * 2));     // [b*64+t][1024]
  u16*   hb   = (u16*)(ws + alloc(2ull * 64 * 1024 * 2));   // bf16 h dbuf
  float* hf   = (float*)(ws + alloc(64ull * 1024 * 4));     // fp32 h_T (encoder)
  float* biasN = (float*)(ws + alloc(4096 * 4));
  float* biasD = (float*)(ws + alloc(4096 * 4));
  float* ce    = (float*)(ws + alloc(64 * 8 * 4));
  u32*   bar   = (u32*)(ws + alloc(2048));
  size_t base_off = off;
  float* XpD2 = (float*)(ws + alloc(4096ull * 4096 * 4));   // dec Xp (fused path)
  if (base_off > ws_size) return;
  const bool fused = (off <= ws_size);
  float* XpD = fused ? XpD2 : Xp;

  conv_all<<<48384, 256, 0, stream>>>(Wih_N, wihN, Whh_N, whhN,
                                      Wih_D, wihD, Whh_D, whhD, W_out, wout);
  prep_small<<<20, 256, 0, stream>>>(cond, emb_cond, bih_N, bhh_N, bih_D, bhh_D,
                                     ce, biasN, biasD, bar);
  gather_kernel<<<4096, 256, 0, stream>>>(emb_N, input_word, Xe, 0);
  gather_kernel<<<4096, 256, 0, stream>>>(emb_D, input_word, Xd, 1);
  init_enc<<<256, 256, 0, stream>>>(ce, hb);

  // encoder Xp
  gemm_bt0<<<512, 512, 0, stream>>>(Xe, wihN, Xp, biasN, 4096, 1024);
  if (fused) {
    // encoder LSTM + decoder-Xp GEMM in one launch (decXp hidden)
    enc_fused<<<640, 512, 0, stream>>>(whhN, Xp, hb, hf, bar + 0,
                                       Xd, wihD, XpD, biasD);
  } else {
    lstm_cluster<<<128, 512, 0, stream>>>(whhN, Xp, hb, nullptr, hf, bar + 0);
  }
  // latent + decoder h0
  latent_hd0_kernel<<<64, 256, 0, stream>>>(hf, W_mean, b_mean, W_logvar, b_logvar,
                                            W_st, b_st, eps, ce, hb);
  if (!fused)
    gemm_bt0<<<512, 512, 0, stream>>>(Xd, wihD, XpD, biasD, 4096, 1024);
  // decoder recurrence
  lstm_cluster<<<128, 512, 0, stream>>>(whhD, XpD, hb, hsd, nullptr, bar + 256);
  // logits[b][t][:] = hsd[b*64+t] @ W_out^T + b_out
  gemm_bt1<<<4096, 512, 0, stream>>>(hsd, wout, out, b_out, 32000, 1024);
}

// Round 18
// 998.194 us; speedup vs baseline: 5.4122x; 1.0132x over previous
//
#include <hip/hip_runtime.h>
#include <hip/hip_bf16.h>

typedef unsigned short u16;
typedef unsigned int   u32;
typedef unsigned long long u64;
typedef __attribute__((ext_vector_type(8))) short short8;   // 8 x bf16 (4 VGPRs)
typedef __attribute__((ext_vector_type(4))) float f32x4;

#define DEVINL static __device__ __forceinline__

// round-to-nearest-even f32 -> bf16
DEVINL u16 f2bf(float x) {
  u32 u = __float_as_uint(x);
  u32 r = (u + 0x7fffu + ((u >> 16) & 1u)) >> 16;
  return (u16)r;
}

// async global->LDS, 16B per lane. LDS dest = uniform base + lane*16.
#define GLD16(gp, lp) __builtin_amdgcn_global_load_lds(                     \
    (const __attribute__((address_space(1))) u32*)(gp),                     \
    (__attribute__((address_space(3))) u32*)(lp), 16, 0, 0)

// ---------------------------------------------------------------------------
// fp32 -> bf16 bulk convert, the four 4Kx1K weight tensors in one launch.
__global__ __launch_bounds__(256) void conv4(
    const float* __restrict__ s0, u16* __restrict__ d0,
    const float* __restrict__ s1, u16* __restrict__ d1,
    const float* __restrict__ s2, u16* __restrict__ d2,
    const float* __restrict__ s3, u16* __restrict__ d3) {
  int blk = blockIdx.x;
  int p = blk >> 12, local = blk & 4095;
  const float* s = (p == 0) ? s0 : (p == 1) ? s1 : (p == 2) ? s2 : s3;
  u16*         d = (p == 0) ? d0 : (p == 1) ? d1 : (p == 2) ? d2 : d3;
  int i = local * 256 + threadIdx.x;
  float4 v = ((const float4*)s)[i];
  ushort4 o;
  o.x = f2bf(v.x); o.y = f2bf(v.y); o.z = f2bf(v.z); o.w = f2bf(v.w);
  ((ushort4*)d)[i] = o;
}

// standalone W_out conversion (fallback path only)
__global__ __launch_bounds__(256) void conv_wout(const float* __restrict__ s,
                                                 u16* __restrict__ d) {
  int i = blockIdx.x * 256 + threadIdx.x;
  float4 v = ((const float4*)s)[i];
  ushort4 o;
  o.x = f2bf(v.x); o.y = f2bf(v.y); o.z = f2bf(v.z); o.w = f2bf(v.w);
  ((ushort4*)d)[i] = o;
}

// cond_e gather + fused bias vectors + zero barrier/progress state
__global__ __launch_bounds__(256) void prep_small(
    const int* __restrict__ cond, const float* __restrict__ emb_cond,
    const float* __restrict__ bihN, const float* __restrict__ bhhN,
    const float* __restrict__ bihD, const float* __restrict__ bhhD,
    float* __restrict__ ce, float* __restrict__ biasN, float* __restrict__ biasD,
    u32* __restrict__ bar) {
  int tid = blockIdx.x * 256 + threadIdx.x;
  if (tid < 512) {
    int b = tid >> 3, j = tid & 7;
    ce[tid] = emb_cond[cond[b] * 8 + j];
  }
  int i = tid - 512;
  if (i >= 0 && i < 4096) {
    biasN[i] = bihN[i] + bhhN[i];
    biasD[i] = bihD[i] + bhhD[i];
  }
  int k = tid - 4608;
  if (k >= 0 && k < 1024) bar[k] = 0;
}

// encoder h0 = [zeros(B,1016), cond_e] -> bf16 into hbuf[0]
__global__ __launch_bounds__(256) void init_enc(const float* __restrict__ ce,
                                                u16* __restrict__ hb0) {
  int tid = blockIdx.x * 256 + threadIdx.x;   // 64*1024
  int b = tid >> 10, col = tid & 1023;
  float v = (col >= 1016) ? ce[b * 8 + (col - 1016)] : 0.f;
  hb0[tid] = f2bf(v);
}

// embedding row gather -> bf16, X[t*64+b][1024]
__global__ __launch_bounds__(256) void gather_kernel(const float* __restrict__ emb,
                                                     const int* __restrict__ words,
                                                     u16* __restrict__ X, int dec) {
  int r = blockIdx.x;                    // r = t*64 + b
  int t = r >> 6, b = r & 63;
  int tok = dec ? ((t == 0) ? 0 : words[b * 64 + t - 1]) : words[b * 64 + t];
  float4 v = ((const float4*)(emb + (size_t)tok * 1024))[threadIdx.x];
  ushort4 o;
  o.x = f2bf(v.x); o.y = f2bf(v.y); o.z = f2bf(v.z); o.w = f2bf(v.w);
  ((ushort4*)(X + (size_t)r * 1024))[threadIdx.x] = o;
}

// ---------------------------------------------------------------------------
// GEMM body, MODE-0 style (n-fast + bijective XCD swizzle), 256x128 tile,
// BK=32, 512 threads = 8 waves (4m x 2n), double-buffered LDS (48KB).
DEVINL void gemm0_body(char* smemc, int bid, int nwg,
                       const u16* __restrict__ A, const u16* __restrict__ B,
                       float* __restrict__ C, const float* __restrict__ bias,
                       int N, int K) {
  u16 (*lA)[256 * 32] = (u16(*)[256 * 32])smemc;
  u16 (*lB)[128 * 32] = (u16(*)[128 * 32])(smemc + 32768);
  const int tid = threadIdx.x;
  const int lane = tid & 63;
  const int wid = tid >> 6;

  const int nn = N >> 7;
  const int wgid = (bid & 7) * (nwg >> 3) + (bid >> 3);
  const int tile_m = (wgid / nn) * 256;
  const int tile_n = (wgid % nn) * 128;
  const int wm = wid >> 1, wn = wid & 1;

  const int ldr = lane >> 2;
  const int lko = (lane & 3) * 8;
  const int l15 = lane & 15;
  const int g4 = lane >> 4;

  const size_t aBase = (size_t)tile_m * K;
  const size_t bBase = (size_t)tile_n * K;

  auto stage = [&](int buf, int k0) {
#pragma unroll
    for (int q = 0; q < 2; ++q) {
      int chk = wid * 2 + q;
      int row = chk * 16 + ldr;
      GLD16(A + aBase + (size_t)row * K + k0 + lko, &lA[buf][chk * 512]);
    }
    int row = wid * 16 + ldr;
    GLD16(B + bBase + (size_t)row * K + k0 + lko, &lB[buf][wid * 512]);
  };

  f32x4 acc[4][4];
#pragma unroll
  for (int i = 0; i < 4; ++i)
#pragma unroll
    for (int j = 0; j < 4; ++j) acc[i][j] = (f32x4)0.f;

  stage(0, 0);
  __syncthreads();

  const int NIT = K >> 5;
  for (int it = 0; it < NIT; ++it) {
    const int cur = it & 1;
    if (it + 1 < NIT) stage(cur ^ 1, (it + 1) * 32);
    short8 af[4], bf[4];
#pragma unroll
    for (int i = 0; i < 4; ++i)
      af[i] = *(const short8*)&lA[cur][(wm * 64 + i * 16 + l15) * 32 + g4 * 8];
#pragma unroll
    for (int j = 0; j < 4; ++j)
      bf[j] = *(const short8*)&lB[cur][(wn * 64 + j * 16 + l15) * 32 + g4 * 8];
#pragma unroll
    for (int i = 0; i < 4; ++i)
#pragma unroll
      for (int j = 0; j < 4; ++j)
        acc[i][j] = __builtin_amdgcn_mfma_f32_16x16x32_bf16(af[i], bf[j], acc[i][j], 0, 0, 0);
    __syncthreads();
  }

#pragma unroll
  for (int i = 0; i < 4; ++i) {
    int row0 = tile_m + wm * 64 + i * 16 + (g4 << 2);
#pragma unroll
    for (int j = 0; j < 4; ++j) {
      int col = tile_n + wn * 64 + j * 16 + l15;
      float bv = bias[col];
#pragma unroll
      for (int e = 0; e < 4; ++e)
        C[(size_t)(row0 + e) * (size_t)N + col] = acc[i][j][e] + bv;
    }
  }
}

// ---------------------------------------------------------------------------
// CLUSTERED PERSISTENT LSTM body (r15/r16-proven skeleton). If prog != null
// (decoder): hs_out is T-MAJOR ([t*64+b][1024]) written via packed-u32
// agent-atomic stores (write-through), and after each cluster barrier the
// j==0 WG publishes prog[c] = steps-complete — consumed by the fused logits
// GEMM blocks in the same dispatch.
DEVINL void lstm_body(char* smemc, const u16* __restrict__ Whh,
                      const float* __restrict__ Xp, u16* __restrict__ hbuf,
                      u16* __restrict__ hs_out, float* __restrict__ hT_out,
                      u32* arrive, u32* prog, int wgi) {
  char* smemA = smemc;
  float (*lg)[16][16] = (float(*)[16][16])(smemc + 32768);
  const int tid = threadIdx.x;      // 0..511
  const int lane = tid & 63;
  const int v = tid >> 6;           // wave 0..7
  const int gate = v >> 1;
  const int ch = v & 1;             // col-half of the WG's 32 cols
  const int c = wgi >> 5;           // cluster 0..3 (batch rows c*16..+16)
  const int j = wgi & 31;           // WG in cluster (cols j*32..+32)
  const int b0 = c * 16, col0 = j * 32;
  const int l15 = lane & 15, g4 = lane >> 4;

  // Whh fragments: loaded ONCE, live across all 64 steps (128 VGPRs)
  short8 breg[32];
  {
    const u16* Brow = Whh + (size_t)(gate * 1024 + col0 + ch * 16 + l15) * 1024
                          + g4 * 8;
#pragma unroll
    for (int kk = 0; kk < 32; ++kk)
      breg[kk] = *(const short8*)(Brow + kk * 32);
  }

  // cell mapping: 512 threads = 16 rows x 32 cols
  const int crow = tid >> 5, colw = tid & 31;
  const int bg = b0 + crow, cgl = col0 + colw;
  const int ch2 = colw >> 4, cw = colw & 15;
  float creg = 0.f;

  // prologue: Xp prefetch for t=0
  float xg0, xg1, xg2, xg3;
  {
    size_t xrow = (size_t)bg * 4096 + cgl;
    xg0 = __builtin_nontemporal_load(&Xp[xrow]);
    xg1 = __builtin_nontemporal_load(&Xp[xrow + 1024]);
    xg2 = __builtin_nontemporal_load(&Xp[xrow + 2048]);
    xg3 = __builtin_nontemporal_load(&Xp[xrow + 3072]);
  }

  for (int t = 0; t < 64; ++t) {
    const char* rbase = (const char*)(hbuf + (size_t)(t & 1) * 65536)
                      + (size_t)b0 * 2048;
    u32* wb32 = (u32*)(hbuf + (size_t)((t + 1) & 1) * 65536);

    // ---- stage h slab (16 rows x 1024 cols) -> swizzled LDS, atomic loads
#pragma unroll
    for (int q = 0; q < 4; ++q) {
      int g = q * 512 + tid;              // 16B chunk id 0..2047
      int row = g >> 7;                   // 0..15
      int cb = (g & 127) * 16;            // byte col in row
      const u64* src = (const u64*)(rbase + (size_t)row * 2048 + cb);
      u64 lo = __hip_atomic_load(src,     __ATOMIC_RELAXED, __HIP_MEMORY_SCOPE_AGENT);
      u64 hi = __hip_atomic_load(src + 1, __ATOMIC_RELAXED, __HIP_MEMORY_SCOPE_AGENT);
      u64* d = (u64*)(smemA + row * 2048 + (cb ^ ((row & 7) << 4)));
      d[0] = lo; d[1] = hi;
    }
    __syncthreads();

    // ---- 32 MFMAs/wave (4 chains), A from swizzled LDS, B from regs
    f32x4 a4[4] = {(f32x4)0.f, (f32x4)0.f, (f32x4)0.f, (f32x4)0.f};
#pragma unroll
    for (int kk = 0; kk < 32; ++kk) {
      int cb2 = kk * 64 + g4 * 16;
      const short8 a = *(const short8*)(smemA + l15 * 2048 + (cb2 ^ ((l15 & 7) << 4)));
      a4[kk & 3] = __builtin_amdgcn_mfma_f32_16x16x32_bf16(a, breg[kk], a4[kk & 3], 0, 0, 0);
    }
    f32x4 asum = a4[0] + a4[1] + a4[2] + a4[3];
    {
      int m = g4 * 4;
#pragma unroll
      for (int e = 0; e < 4; ++e) lg[v][m + e][l15] = asum[e];
    }
    __syncthreads();

    // ---- cell update: 1 cell per thread (uses prefetched xg)
    {
      float gi = lg[0 + ch2][crow][cw] + xg0;
      float gf = lg[2 + ch2][crow][cw] + xg1;
      float gg = lg[4 + ch2][crow][cw] + xg2;
      float go = lg[6 + ch2][crow][cw] + xg3;
      float si = 1.f / (1.f + __expf(-gi));
      float sf = 1.f / (1.f + __expf(-gf));
      float so = 1.f / (1.f + __expf(-go));
      float tg = tanhf(gg);
      float cn = sf * creg + si * tg;
      float hn = so * tanhf(cn);
      creg = cn;
      u16 h16 = f2bf(hn);
      u32 mine = h16;
      u32 other = (u32)__shfl_xor((int)mine, 1);
      if (!(colw & 1)) {
        u32 pk = mine | (other << 16);
        __hip_atomic_store(wb32 + (((size_t)bg * 1024 + cgl) >> 1), pk,
                           __ATOMIC_RELAXED, __HIP_MEMORY_SCOPE_AGENT);
        if (hs_out)   // t-major, write-through (consumed intra-dispatch)
          __hip_atomic_store((u32*)hs_out + ((((size_t)t * 64 + bg) * 1024 + cgl) >> 1),
                             pk, __ATOMIC_RELAXED, __HIP_MEMORY_SCOPE_AGENT);
      }
      if (hT_out && t == 63) hT_out[bg * 1024 + cgl] = hn;   // cross-kernel
    }

    // ---- prefetch next-step Xp, then flat fence-free cluster barrier
    if (t != 63) {
      {
        size_t xrow = (size_t)((t + 1) * 64 + bg) * 4096 + cgl;
        xg0 = __builtin_nontemporal_load(&Xp[xrow]);
        xg1 = __builtin_nontemporal_load(&Xp[xrow + 1024]);
        xg2 = __builtin_nontemporal_load(&Xp[xrow + 2048]);
        xg3 = __builtin_nontemporal_load(&Xp[xrow + 3072]);
      }
      u32 want = (u32)(t + 1);
      asm volatile("s_waitcnt vmcnt(0)" ::: "memory");   // drains h/hsd stores + Xp
      __syncthreads();
      if (tid == 0)
        __hip_atomic_store(&arrive[wgi], want, __ATOMIC_RELAXED,
                           __HIP_MEMORY_SCOPE_AGENT);
      if (tid < 32) {
        int guard = 0;
        while (__hip_atomic_load(&arrive[c * 32 + tid], __ATOMIC_RELAXED,
                                 __HIP_MEMORY_SCOPE_AGENT) < want) {
          __builtin_amdgcn_s_sleep(2);
          if (++guard > (1 << 20)) break;   // safety valve
        }
      }
      __syncthreads();
      if (prog && j == 0 && tid == 0)
        __hip_atomic_store(&prog[c], want, __ATOMIC_RELAXED,
                           __HIP_MEMORY_SCOPE_AGENT);
    }
  }

  // ---- final drain + publish prog = 64 (decoder only)
  if (prog) {
    asm volatile("s_waitcnt vmcnt(0)" ::: "memory");
    __syncthreads();
    if (tid == 0)
      __hip_atomic_store(&arrive[wgi], 64u, __ATOMIC_RELAXED,
                         __HIP_MEMORY_SCOPE_AGENT);
    if (j == 0) {
      if (tid < 32) {
        int guard = 0;
        while (__hip_atomic_load(&arrive[c * 32 + tid], __ATOMIC_RELAXED,
                                 __HIP_MEMORY_SCOPE_AGENT) < 64u) {
          __builtin_amdgcn_s_sleep(2);
          if (++guard > (1 << 20)) break;
        }
      }
      __syncthreads();
      if (tid == 0)
        __hip_atomic_store(&prog[c], 64u, __ATOMIC_RELAXED,
                           __HIP_MEMORY_SCOPE_AGENT);
    }
  }
}

// ---------------------------------------------------------------------------
// Standalone LSTM wrapper (encoder fallback path).
__global__ __launch_bounds__(512, 1) void lstm_cluster(
    const u16* __restrict__ Whh, const float* __restrict__ Xp,
    u16* __restrict__ hbuf, float* __restrict__ hT_out, u32* arrive) {
  __shared__ __align__(16) char smem[40960];
  lstm_body(smem, Whh, Xp, hbuf, nullptr, hT_out, arrive, nullptr, blockIdx.x);
}

__global__ __launch_bounds__(512) void gemm_bt0(
    const u16* __restrict__ A, const u16* __restrict__ B,
    float* __restrict__ C, const float* __restrict__ bias, int N, int K) {
  __shared__ __align__(16) char smem[49152];
  gemm0_body(smem, blockIdx.x, gridDim.x, A, B, C, bias, N, K);
}

// Fused encoder: blocks 0..127 = encoder LSTM (co-resident); 128..639 =
// decoder-Xp GEMM; 640..1151 = W_out fp32->bf16 conversion (grid-stride).
__global__ __launch_bounds__(512, 1) void enc_fused(
    const u16* __restrict__ whhN, const float* __restrict__ XpE,
    u16* __restrict__ hbuf, float* __restrict__ hT_out, u32* arrive,
    const u16* __restrict__ Xd, const u16* __restrict__ wihD,
    float* __restrict__ XpD, const float* __restrict__ biasD,
    const float* __restrict__ Wout, u16* __restrict__ wout) {
  __shared__ __align__(16) char smem[49152];
  if (blockIdx.x < 128) {
    lstm_body(smem, whhN, XpE, hbuf, nullptr, hT_out, arrive, nullptr, blockIdx.x);
  } else if (blockIdx.x < 640) {
    gemm0_body(smem, blockIdx.x - 128, 512, Xd, wihD, XpD, biasD, 4096, 1024);
  } else {
    int tid0 = (blockIdx.x - 640) * 512 + threadIdx.x;
    for (int i = tid0; i < 8192000; i += 512 * 512) {
      float4 v = ((const float4*)Wout)[i];
      ushort4 o;
      o.x = f2bf(v.x); o.y = f2bf(v.y); o.z = f2bf(v.z); o.w = f2bf(v.w);
      ((ushort4*)wout)[i] = o;
    }
  }
}

// ---------------------------------------------------------------------------
// Fused decoder: blocks 0..127 = decoder LSTM (t-major hsd + prog publish);
// blocks 128..4223 = logits GEMM, per-XCD n-partition; each m-tile is a
// 4-t-chunk gated on prog[0..3] >= 4*mt+4. REMAP NT store to out[b*64+t].
__global__ __launch_bounds__(512, 1) void dec_fused(
    const u16* __restrict__ whhD, const float* __restrict__ XpD,
    u16* __restrict__ hbuf, u16* __restrict__ hsd, u32* arrive, u32* prog,
    const u16* __restrict__ wout, float* __restrict__ out,
    const float* __restrict__ b_out) {
  __shared__ __align__(16) char smem[49152];
  if (blockIdx.x < 128) {
    lstm_body(smem, whhD, XpD, hbuf, hsd, nullptr, arrive, prog, blockIdx.x);
    return;
  }
  // ---- logits GEMM part
  u16 (*lA)[256 * 32] = (u16(*)[256 * 32])smem;
  u16 (*lB)[128 * 32] = (u16(*)[128 * 32])(smem + 32768);
  const int tid = threadIdx.x;
  const int lane = tid & 63;
  const int wid = tid >> 6;

  const int i = blockIdx.x - 128;  // 0..4095
  const int x = i & 7;             // XCD id
  const int k = i >> 3;
  const int mg = k >> 6;
  const int r  = k & 63;
  const int kn = r >> 1;
  const int mi = r & 1;
  const int tn = kn * 8 + x;
  if (tn >= 250) return;           // dummy (whole WG exits)
  const int mt = mg * 2 + mi;      // m-tile = t-chunk [mt*4, mt*4+4)
  const int tile_m = mt * 256;
  const int tile_n = tn * 128;
  const int wm = wid >> 1, wn = wid & 1;
  const int N = 32000, K = 1024;

  // ---- wait until decoder steps 0..mt*4+3 are complete in all clusters
  {
    u32 need = (u32)(mt * 4 + 4);
    if (tid < 4) {
      int guard = 0;
      while (__hip_atomic_load(&prog[tid], __ATOMIC_RELAXED,
                               __HIP_MEMORY_SCOPE_AGENT) < need) {
        __builtin_amdgcn_s_sleep(8);
        if (++guard > (1 << 22)) break;   // safety valve
      }
    }
    __syncthreads();
  }

  const int ldr = lane >> 2;
  const int lko = (lane & 3) * 8;
  const int l15 = lane & 15;
  const int g4 = lane >> 4;

  const size_t aBase = (size_t)tile_m * K;
  const size_t bBase = (size_t)tile_n * K;

  f32x4 acc[4][4];
#pragma unroll
  for (int i2 = 0; i2 < 4; ++i2)
#pragma unroll
    for (int j2 = 0; j2 < 4; ++j2) acc[i2][j2] = (f32x4)0.f;

  auto stg = [&](int buf, int k0) {
#pragma unroll
    for (int q = 0; q < 2; ++q) {
      int chk = wid * 2 + q;
      int row = chk * 16 + ldr;
      GLD16(hsd + aBase + (size_t)row * K + k0 + lko, &lA[buf][chk * 512]);
    }
    int row = wid * 16 + ldr;
    GLD16(wout + bBase + (size_t)row * K + k0 + lko, &lB[buf][wid * 512]);
  };

  stg(0, 0);
  __syncthreads();

  const int NIT = K >> 5;
  for (int it = 0; it < NIT; ++it) {
    const int cur = it & 1;
    if (it + 1 < NIT) stg(cur ^ 1, (it + 1) * 32);
    short8 af[4], bf[4];
#pragma unroll
    for (int i2 = 0; i2 < 4; ++i2)
      af[i2] = *(const short8*)&lA[cur][(wm * 64 + i2 * 16 + l15) * 32 + g4 * 8];
#pragma unroll
    for (int j2 = 0; j2 < 4; ++j2)
      bf[j2] = *(const short8*)&lB[cur][(wn * 64 + j2 * 16 + l15) * 32 + g4 * 8];
#pragma unroll
    for (int i2 = 0; i2 < 4; ++i2)
#pragma unroll
      for (int j2 = 0; j2 < 4; ++j2)
        acc[i2][j2] = __builtin_amdgcn_mfma_f32_16x16x32_bf16(af[i2], bf[j2], acc[i2][j2], 0, 0, 0);
    __syncthreads();
  }

#pragma unroll
  for (int i2 = 0; i2 < 4; ++i2) {
    int row0 = tile_m + wm * 64 + i2 * 16 + (g4 << 2);
#pragma unroll
    for (int j2 = 0; j2 < 4; ++j2) {
      int col = tile_n + wn * 64 + j2 * 16 + l15;
      float bv = b_out[col];
#pragma unroll
      for (int e = 0; e < 4; ++e) {
        int rr = row0 + e;                       // t-major row = t*64+b
        size_t o = (size_t)((rr & 63) * 64 + (rr >> 6)) * (size_t)N + col;
        __builtin_nontemporal_store(acc[i2][j2][e] + bv, &out[o]);
      }
    }
  }
}

// ---------------------------------------------------------------------------
// mean/logvar/latent + hd0 = [latent|cond_e] @ W_st^T + b_st -> bf16 h0.
__global__ __launch_bounds__(256) void latent_hd0_kernel(
    const float* hT, const float* Wm, const float* bm,
    const float* Wl, const float* bl, const float* Wst, const float* bst,
    const float* eps, const float* ce, u16* hb0) {
  __shared__ float red[64][4];
  __shared__ float ml[64];
  __shared__ float lat[40];
  int b = blockIdx.x;
  int tid = threadIdx.x;
  int o = tid >> 2, p = tid & 3;
  const float* w = (o < 32) ? (Wm + (size_t)o * 1024) : (Wl + (size_t)(o - 32) * 1024);
  const float* h = hT + (size_t)b * 1024;
  float s = 0.f;
  for (int k = p * 256; k < p * 256 + 256; ++k) s += h[k] * w[k];
  red[o][p] = s;
  __syncthreads();
  if (tid < 64) {
    float v = red[tid][0] + red[tid][1] + red[tid][2] + red[tid][3];
    v += (tid < 32) ? bm[tid] : bl[tid - 32];
    ml[tid] = v;
  }
  __syncthreads();
  if (tid < 32) lat[tid] = eps[b * 32 + tid] * __expf(0.5f * ml[32 + tid]) + ml[tid];
  if (tid >= 32 && tid < 40) lat[tid] = ce[b * 8 + (tid - 32)];
  __syncthreads();
  for (int hc = tid; hc < 1024; hc += 256) {
    float s2 = bst[hc];
    const float* wr = Wst + (size_t)hc * 40;
#pragma unroll
    for (int j = 0; j < 40; ++j) s2 += lat[j] * wr[j];
    hb0[b * 1024 + hc] = f2bf(s2);
  }
}

// ---------------------------------------------------------------------------
extern "C" void kernel_launch(void* const* d_in, const int* in_sizes, int n_in,
                              void* d_out, int out_size, void* d_ws, size_t ws_size,
                              hipStream_t stream) {
  const int*   input_word = (const int*)d_in[0];
  const int*   cond       = (const int*)d_in[1];
  const float* emb_N      = (const float*)d_in[2];
  const float* Wih_N      = (const float*)d_in[3];
  const float* Whh_N      = (const float*)d_in[4];
  const float* bih_N      = (const float*)d_in[5];
  const float* bhh_N      = (const float*)d_in[6];
  const float* emb_D      = (const float*)d_in[7];
  const float* Wih_D      = (const float*)d_in[8];
  const float* Whh_D      = (const float*)d_in[9];
  const float* bih_D      = (const float*)d_in[10];
  const float* bhh_D      = (const float*)d_in[11];
  const float* emb_cond   = (const float*)d_in[12];
  const float* W_mean     = (const float*)d_in[13];
  const float* b_mean     = (const float*)d_in[14];
  const float* W_logvar   = (const float*)d_in[15];
  const float* b_logvar   = (const float*)d_in[16];
  const float* W_st       = (const float*)d_in[17];
  const float* b_st       = (const float*)d_in[18];
  const float* W_out      = (const float*)d_in[19];
  const float* b_out      = (const float*)d_in[20];
  const float* eps        = (const float*)d_in[21];
  float* out = (float*)d_out;

  char* ws = (char*)d_ws;
  size_t off = 0;
  auto alloc = [&](size_t b) { size_t p = off; off += (b + 255) & ~(size_t)255; return p; };
  u16*   wihN = (u16*)(ws + alloc(4096ull * 1024 * 2));
  u16*   whhN = (u16*)(ws + alloc(4096ull * 1024 * 2));
  u16*   wihD = (u16*)(ws + alloc(4096ull * 1024 * 2));
  u16*   whhD = (u16*)(ws + alloc(4096ull * 1024 * 2));
  u16*   wout = (u16*)(ws + alloc(32000ull * 1024 * 2));
  u16*   Xe   = (u16*)(ws + alloc(4096ull * 1024 * 2));
  u16*   Xd   = (u16*)(ws + alloc(4096ull * 1024 * 2));
  float* Xp   = (float*)(ws + alloc(4096ull * 4096 * 4));   // enc (and dec fallback)
  u16*   hsd  = (u16*)(ws + alloc(4096ull * 1024 * 2));     // T-MAJOR [t*64+b][1024]
  u16*   hb   = (u16*)(ws + alloc(2ull * 64 * 1024 * 2));   // bf16 h dbuf
  float* hf   = (float*)(ws + alloc(64ull * 1024 * 4));     // fp32 h_T (encoder)
  float* biasN = (float*)(ws + alloc(4096 * 4));
  float* biasD = (float*)(ws + alloc(4096 * 4));
  float* ce    = (float*)(ws + alloc(64 * 8 * 4));
  u32*   bar   = (u32*)(ws + alloc(4096));
  // bar: enc arrive [0..127], dec arrive [256..383], dec prog [512..515]
  size_t base_off = off;
  float* XpD2 = (float*)(ws + alloc(4096ull * 4096 * 4));   // dec Xp (fused path)
  if (base_off > ws_size) return;
  const bool fused = (off <= ws_size);
  float* XpD = fused ? XpD2 : Xp;

  conv4<<<16384, 256, 0, stream>>>(Wih_N, wihN, Whh_N, whhN,
                                   Wih_D, wihD, Whh_D, whhD);
  prep_small<<<22, 256, 0, stream>>>(cond, emb_cond, bih_N, bhh_N, bih_D, bhh_D,
                                     ce, biasN, biasD, bar);
  gather_kernel<<<4096, 256, 0, stream>>>(emb_N, input_word, Xe, 0);
  gather_kernel<<<4096, 256, 0, stream>>>(emb_D, input_word, Xd, 1);
  init_enc<<<256, 256, 0, stream>>>(ce, hb);

  // encoder Xp
  gemm_bt0<<<512, 512, 0, stream>>>(Xe, wihN, Xp, biasN, 4096, 1024);
  if (fused) {
    // encoder LSTM + decoder-Xp GEMM + W_out conversion, one launch
    enc_fused<<<1152, 512, 0, stream>>>(whhN, Xp, hb, hf, bar + 0,
                                        Xd, wihD, XpD, biasD, W_out, wout);
  } else {
    conv_wout<<<32000, 256, 0, stream>>>(W_out, wout);
    lstm_cluster<<<128, 512, 0, stream>>>(whhN, Xp, hb, hf, bar + 0);
  }
  // latent + decoder h0
  latent_hd0_kernel<<<64, 256, 0, stream>>>(hf, W_mean, b_mean, W_logvar, b_logvar,
                                            W_st, b_st, eps, ce, hb);
  if (!fused)
    gemm_bt0<<<512, 512, 0, stream>>>(Xd, wihD, XpD, biasD, 4096, 1024);
  // decoder LSTM + logits GEMM fused (producer-consumer on hsd via prog[])
  dec_fused<<<4224, 512, 0, stream>>>(whhD, XpD, hb, hsd, bar + 256, bar + 512,
                                      wout, out, b_out);
}

// Round 19
// 994.514 us; speedup vs baseline: 5.4322x; 1.0037x over previous
//
#include <hip/hip_runtime.h>
#include <hip/hip_bf16.h>

typedef unsigned short u16;
typedef unsigned int   u32;
typedef unsigned long long u64;
typedef __attribute__((ext_vector_type(8))) short short8;   // 8 x bf16 (4 VGPRs)
typedef __attribute__((ext_vector_type(4))) float f32x4;

#define DEVINL static __device__ __forceinline__

// round-to-nearest-even f32 -> bf16
DEVINL u16 f2bf(float x) {
  u32 u = __float_as_uint(x);
  u32 r = (u + 0x7fffu + ((u >> 16) & 1u)) >> 16;
  return (u16)r;
}

// async global->LDS, 16B per lane. LDS dest = uniform base + lane*16.
#define GLD16(gp, lp) __builtin_amdgcn_global_load_lds(                     \
    (const __attribute__((address_space(1))) u32*)(gp),                     \
    (__attribute__((address_space(3))) u32*)(lp), 16, 0, 0)

// ---------------------------------------------------------------------------
// fp32 -> bf16 bulk convert, the four 4Kx1K weight tensors in one launch.
__global__ __launch_bounds__(256) void conv4(
    const float* __restrict__ s0, u16* __restrict__ d0,
    const float* __restrict__ s1, u16* __restrict__ d1,
    const float* __restrict__ s2, u16* __restrict__ d2,
    const float* __restrict__ s3, u16* __restrict__ d3) {
  int blk = blockIdx.x;
  int p = blk >> 12, local = blk & 4095;
  const float* s = (p == 0) ? s0 : (p == 1) ? s1 : (p == 2) ? s2 : s3;
  u16*         d = (p == 0) ? d0 : (p == 1) ? d1 : (p == 2) ? d2 : d3;
  int i = local * 256 + threadIdx.x;
  float4 v = ((const float4*)s)[i];
  ushort4 o;
  o.x = f2bf(v.x); o.y = f2bf(v.y); o.z = f2bf(v.z); o.w = f2bf(v.w);
  ((ushort4*)d)[i] = o;
}

// standalone W_out conversion (fallback path only)
__global__ __launch_bounds__(256) void conv_wout(const float* __restrict__ s,
                                                 u16* __restrict__ d) {
  int i = blockIdx.x * 256 + threadIdx.x;
  float4 v = ((const float4*)s)[i];
  ushort4 o;
  o.x = f2bf(v.x); o.y = f2bf(v.y); o.z = f2bf(v.z); o.w = f2bf(v.w);
  ((ushort4*)d)[i] = o;
}

// cond_e gather + fused bias vectors + zero barrier/progress state
__global__ __launch_bounds__(256) void prep_small(
    const int* __restrict__ cond, const float* __restrict__ emb_cond,
    const float* __restrict__ bihN, const float* __restrict__ bhhN,
    const float* __restrict__ bihD, const float* __restrict__ bhhD,
    float* __restrict__ ce, float* __restrict__ biasN, float* __restrict__ biasD,
    u32* __restrict__ bar) {
  int tid = blockIdx.x * 256 + threadIdx.x;
  if (tid < 512) {
    int b = tid >> 3, j = tid & 7;
    ce[tid] = emb_cond[cond[b] * 8 + j];
  }
  int i = tid - 512;
  if (i >= 0 && i < 4096) {
    biasN[i] = bihN[i] + bhhN[i];
    biasD[i] = bihD[i] + bhhD[i];
  }
  int k = tid - 4608;
  if (k >= 0 && k < 1024) bar[k] = 0;
}

// encoder h0 = [zeros(B,1016), cond_e] -> bf16 into hbuf[0]
__global__ __launch_bounds__(256) void init_enc(const float* __restrict__ ce,
                                                u16* __restrict__ hb0) {
  int tid = blockIdx.x * 256 + threadIdx.x;   // 64*1024
  int b = tid >> 10, col = tid & 1023;
  float v = (col >= 1016) ? ce[b * 8 + (col - 1016)] : 0.f;
  hb0[tid] = f2bf(v);
}

// embedding row gather -> bf16, X[t*64+b][1024]
__global__ __launch_bounds__(256) void gather_kernel(const float* __restrict__ emb,
                                                     const int* __restrict__ words,
                                                     u16* __restrict__ X, int dec) {
  int r = blockIdx.x;                    // r = t*64 + b
  int t = r >> 6, b = r & 63;
  int tok = dec ? ((t == 0) ? 0 : words[b * 64 + t - 1]) : words[b * 64 + t];
  float4 v = ((const float4*)(emb + (size_t)tok * 1024))[threadIdx.x];
  ushort4 o;
  o.x = f2bf(v.x); o.y = f2bf(v.y); o.z = f2bf(v.z); o.w = f2bf(v.w);
  ((ushort4*)(X + (size_t)r * 1024))[threadIdx.x] = o;
}

// ---------------------------------------------------------------------------
// GEMM body, MODE-0 style (n-fast + bijective XCD swizzle), 256x128 tile,
// BK=32, 512 threads = 8 waves (4m x 2n), double-buffered LDS (48KB).
DEVINL void gemm0_body(char* smemc, int bid, int nwg,
                       const u16* __restrict__ A, const u16* __restrict__ B,
                       float* __restrict__ C, const float* __restrict__ bias,
                       int N, int K) {
  u16 (*lA)[256 * 32] = (u16(*)[256 * 32])smemc;
  u16 (*lB)[128 * 32] = (u16(*)[128 * 32])(smemc + 32768);
  const int tid = threadIdx.x;
  const int lane = tid & 63;
  const int wid = tid >> 6;

  const int nn = N >> 7;
  const int wgid = (bid & 7) * (nwg >> 3) + (bid >> 3);
  const int tile_m = (wgid / nn) * 256;
  const int tile_n = (wgid % nn) * 128;
  const int wm = wid >> 1, wn = wid & 1;

  const int ldr = lane >> 2;
  const int lko = (lane & 3) * 8;
  const int l15 = lane & 15;
  const int g4 = lane >> 4;

  const size_t aBase = (size_t)tile_m * K;
  const size_t bBase = (size_t)tile_n * K;

  auto stage = [&](int buf, int k0) {
#pragma unroll
    for (int q = 0; q < 2; ++q) {
      int chk = wid * 2 + q;
      int row = chk * 16 + ldr;
      GLD16(A + aBase + (size_t)row * K + k0 + lko, &lA[buf][chk * 512]);
    }
    int row = wid * 16 + ldr;
    GLD16(B + bBase + (size_t)row * K + k0 + lko, &lB[buf][wid * 512]);
  };

  f32x4 acc[4][4];
#pragma unroll
  for (int i = 0; i < 4; ++i)
#pragma unroll
    for (int j = 0; j < 4; ++j) acc[i][j] = (f32x4)0.f;

  stage(0, 0);
  __syncthreads();

  const int NIT = K >> 5;
  for (int it = 0; it < NIT; ++it) {
    const int cur = it & 1;
    if (it + 1 < NIT) stage(cur ^ 1, (it + 1) * 32);
    short8 af[4], bf[4];
#pragma unroll
    for (int i = 0; i < 4; ++i)
      af[i] = *(const short8*)&lA[cur][(wm * 64 + i * 16 + l15) * 32 + g4 * 8];
#pragma unroll
    for (int j = 0; j < 4; ++j)
      bf[j] = *(const short8*)&lB[cur][(wn * 64 + j * 16 + l15) * 32 + g4 * 8];
#pragma unroll
    for (int i = 0; i < 4; ++i)
#pragma unroll
      for (int j = 0; j < 4; ++j)
        acc[i][j] = __builtin_amdgcn_mfma_f32_16x16x32_bf16(af[i], bf[j], acc[i][j], 0, 0, 0);
    __syncthreads();
  }

#pragma unroll
  for (int i = 0; i < 4; ++i) {
    int row0 = tile_m + wm * 64 + i * 16 + (g4 << 2);
#pragma unroll
    for (int j = 0; j < 4; ++j) {
      int col = tile_n + wn * 64 + j * 16 + l15;
      float bv = bias[col];
#pragma unroll
      for (int e = 0; e < 4; ++e)
        C[(size_t)(row0 + e) * (size_t)N + col] = acc[i][j][e] + bv;
    }
  }
}

// ---------------------------------------------------------------------------
// CLUSTERED PERSISTENT LSTM body (r15/r16-proven skeleton). Waves run at
// s_setprio(2) for the whole loop: co-resident priority-0 GEMM/conv waves
// soak idle issue slots without stretching the LSTM's latency-critical
// step chain (the r18 fusion penalty). If prog != null (decoder): hs_out is
// T-MAJOR, written via packed-u32 agent-atomic stores; after each cluster
// barrier the j==0 WG publishes prog[c] = steps complete.
DEVINL void lstm_body(char* smemc, const u16* __restrict__ Whh,
                      const float* __restrict__ Xp, u16* __restrict__ hbuf,
                      u16* __restrict__ hs_out, float* __restrict__ hT_out,
                      u32* arrive, u32* prog, int wgi) {
  __builtin_amdgcn_s_setprio(2);    // LSTM waves win issue arbitration
  char* smemA = smemc;
  float (*lg)[16][16] = (float(*)[16][16])(smemc + 32768);
  const int tid = threadIdx.x;      // 0..511
  const int lane = tid & 63;
  const int v = tid >> 6;           // wave 0..7
  const int gate = v >> 1;
  const int ch = v & 1;             // col-half of the WG's 32 cols
  const int c = wgi >> 5;           // cluster 0..3 (batch rows c*16..+16)
  const int j = wgi & 31;           // WG in cluster (cols j*32..+32)
  const int b0 = c * 16, col0 = j * 32;
  const int l15 = lane & 15, g4 = lane >> 4;

  // Whh fragments: loaded ONCE, live across all 64 steps (128 VGPRs)
  short8 breg[32];
  {
    const u16* Brow = Whh + (size_t)(gate * 1024 + col0 + ch * 16 + l15) * 1024
                          + g4 * 8;
#pragma unroll
    for (int kk = 0; kk < 32; ++kk)
      breg[kk] = *(const short8*)(Brow + kk * 32);
  }

  // cell mapping: 512 threads = 16 rows x 32 cols
  const int crow = tid >> 5, colw = tid & 31;
  const int bg = b0 + crow, cgl = col0 + colw;
  const int ch2 = colw >> 4, cw = colw & 15;
  float creg = 0.f;

  // prologue: Xp prefetch for t=0
  float xg0, xg1, xg2, xg3;
  {
    size_t xrow = (size_t)bg * 4096 + cgl;
    xg0 = __builtin_nontemporal_load(&Xp[xrow]);
    xg1 = __builtin_nontemporal_load(&Xp[xrow + 1024]);
    xg2 = __builtin_nontemporal_load(&Xp[xrow + 2048]);
    xg3 = __builtin_nontemporal_load(&Xp[xrow + 3072]);
  }

  for (int t = 0; t < 64; ++t) {
    const char* rbase = (const char*)(hbuf + (size_t)(t & 1) * 65536)
                      + (size_t)b0 * 2048;
    u32* wb32 = (u32*)(hbuf + (size_t)((t + 1) & 1) * 65536);

    // ---- stage h slab (16 rows x 1024 cols) -> swizzled LDS, atomic loads
#pragma unroll
    for (int q = 0; q < 4; ++q) {
      int g = q * 512 + tid;              // 16B chunk id 0..2047
      int row = g >> 7;                   // 0..15
      int cb = (g & 127) * 16;            // byte col in row
      const u64* src = (const u64*)(rbase + (size_t)row * 2048 + cb);
      u64 lo = __hip_atomic_load(src,     __ATOMIC_RELAXED, __HIP_MEMORY_SCOPE_AGENT);
      u64 hi = __hip_atomic_load(src + 1, __ATOMIC_RELAXED, __HIP_MEMORY_SCOPE_AGENT);
      u64* d = (u64*)(smemA + row * 2048 + (cb ^ ((row & 7) << 4)));
      d[0] = lo; d[1] = hi;
    }
    __syncthreads();

    // ---- 32 MFMAs/wave (4 chains), A from swizzled LDS, B from regs
    f32x4 a4[4] = {(f32x4)0.f, (f32x4)0.f, (f32x4)0.f, (f32x4)0.f};
#pragma unroll
    for (int kk = 0; kk < 32; ++kk) {
      int cb2 = kk * 64 + g4 * 16;
      const short8 a = *(const short8*)(smemA + l15 * 2048 + (cb2 ^ ((l15 & 7) << 4)));
      a4[kk & 3] = __builtin_amdgcn_mfma_f32_16x16x32_bf16(a, breg[kk], a4[kk & 3], 0, 0, 0);
    }
    f32x4 asum = a4[0] + a4[1] + a4[2] + a4[3];
    {
      int m = g4 * 4;
#pragma unroll
      for (int e = 0; e < 4; ++e) lg[v][m + e][l15] = asum[e];
    }
    __syncthreads();

    // ---- cell update: 1 cell per thread (uses prefetched xg)
    {
      float gi = lg[0 + ch2][crow][cw] + xg0;
      float gf = lg[2 + ch2][crow][cw] + xg1;
      float gg = lg[4 + ch2][crow][cw] + xg2;
      float go = lg[6 + ch2][crow][cw] + xg3;
      float si = 1.f / (1.f + __expf(-gi));
      float sf = 1.f / (1.f + __expf(-gf));
      float so = 1.f / (1.f + __expf(-go));
      float tg = tanhf(gg);
      float cn = sf * creg + si * tg;
      float hn = so * tanhf(cn);
      creg = cn;
      u16 h16 = f2bf(hn);
      u32 mine = h16;
      u32 other = (u32)__shfl_xor((int)mine, 1);
      if (!(colw & 1)) {
        u32 pk = mine | (other << 16);
        __hip_atomic_store(wb32 + (((size_t)bg * 1024 + cgl) >> 1), pk,
                           __ATOMIC_RELAXED, __HIP_MEMORY_SCOPE_AGENT);
        if (hs_out)   // t-major, write-through (consumed intra-dispatch)
          __hip_atomic_store((u32*)hs_out + ((((size_t)t * 64 + bg) * 1024 + cgl) >> 1),
                             pk, __ATOMIC_RELAXED, __HIP_MEMORY_SCOPE_AGENT);
      }
      if (hT_out && t == 63) hT_out[bg * 1024 + cgl] = hn;   // cross-kernel
    }

    // ---- prefetch next-step Xp, then flat fence-free cluster barrier
    if (t != 63) {
      {
        size_t xrow = (size_t)((t + 1) * 64 + bg) * 4096 + cgl;
        xg0 = __builtin_nontemporal_load(&Xp[xrow]);
        xg1 = __builtin_nontemporal_load(&Xp[xrow + 1024]);
        xg2 = __builtin_nontemporal_load(&Xp[xrow + 2048]);
        xg3 = __builtin_nontemporal_load(&Xp[xrow + 3072]);
      }
      u32 want = (u32)(t + 1);
      asm volatile("s_waitcnt vmcnt(0)" ::: "memory");   // drains h/hsd stores + Xp
      __syncthreads();
      if (tid == 0)
        __hip_atomic_store(&arrive[wgi], want, __ATOMIC_RELAXED,
                           __HIP_MEMORY_SCOPE_AGENT);
      if (tid < 32) {
        int guard = 0;
        while (__hip_atomic_load(&arrive[c * 32 + tid], __ATOMIC_RELAXED,
                                 __HIP_MEMORY_SCOPE_AGENT) < want) {
          __builtin_amdgcn_s_sleep(2);
          if (++guard > (1 << 20)) break;   // safety valve
        }
      }
      __syncthreads();
      if (prog && j == 0 && tid == 0)
        __hip_atomic_store(&prog[c], want, __ATOMIC_RELAXED,
                           __HIP_MEMORY_SCOPE_AGENT);
    }
  }

  // ---- final drain + publish prog = 64 (decoder only)
  if (prog) {
    asm volatile("s_waitcnt vmcnt(0)" ::: "memory");
    __syncthreads();
    if (tid == 0)
      __hip_atomic_store(&arrive[wgi], 64u, __ATOMIC_RELAXED,
                         __HIP_MEMORY_SCOPE_AGENT);
    if (j == 0) {
      if (tid < 32) {
        int guard = 0;
        while (__hip_atomic_load(&arrive[c * 32 + tid], __ATOMIC_RELAXED,
                                 __HIP_MEMORY_SCOPE_AGENT) < 64u) {
          __builtin_amdgcn_s_sleep(2);
          if (++guard > (1 << 20)) break;
        }
      }
      __syncthreads();
      if (tid == 0)
        __hip_atomic_store(&prog[c], 64u, __ATOMIC_RELAXED,
                           __HIP_MEMORY_SCOPE_AGENT);
    }
  }
  __builtin_amdgcn_s_setprio(0);
}

// ---------------------------------------------------------------------------
// Standalone LSTM wrapper (encoder fallback path).
__global__ __launch_bounds__(512, 1) void lstm_cluster(
    const u16* __restrict__ Whh, const float* __restrict__ Xp,
    u16* __restrict__ hbuf, float* __restrict__ hT_out, u32* arrive) {
  __shared__ __align__(16) char smem[40960];
  lstm_body(smem, Whh, Xp, hbuf, nullptr, hT_out, arrive, nullptr, blockIdx.x);
}

__global__ __launch_bounds__(512) void gemm_bt0(
    const u16* __restrict__ A, const u16* __restrict__ B,
    float* __restrict__ C, const float* __restrict__ bias, int N, int K) {
  __shared__ __align__(16) char smem[49152];
  gemm0_body(smem, blockIdx.x, gridDim.x, A, B, C, bias, N, K);
}

// Fused encoder: blocks 0..127 = encoder LSTM (co-resident, prio 2);
// 128..639 = decoder-Xp GEMM; 640..1151 = W_out conversion (grid-stride).
__global__ __launch_bounds__(512, 1) void enc_fused(
    const u16* __restrict__ whhN, const float* __restrict__ XpE,
    u16* __restrict__ hbuf, float* __restrict__ hT_out, u32* arrive,
    const u16* __restrict__ Xd, const u16* __restrict__ wihD,
    float* __restrict__ XpD, const float* __restrict__ biasD,
    const float* __restrict__ Wout, u16* __restrict__ wout) {
  __shared__ __align__(16) char smem[49152];
  if (blockIdx.x < 128) {
    lstm_body(smem, whhN, XpE, hbuf, nullptr, hT_out, arrive, nullptr, blockIdx.x);
  } else if (blockIdx.x < 640) {
    gemm0_body(smem, blockIdx.x - 128, 512, Xd, wihD, XpD, biasD, 4096, 1024);
  } else {
    int tid0 = (blockIdx.x - 640) * 512 + threadIdx.x;
    for (int i = tid0; i < 8192000; i += 512 * 512) {
      float4 v = ((const float4*)Wout)[i];
      ushort4 o;
      o.x = f2bf(v.x); o.y = f2bf(v.y); o.z = f2bf(v.z); o.w = f2bf(v.w);
      ((ushort4*)wout)[i] = o;
    }
  }
}

// ---------------------------------------------------------------------------
// Fused decoder: blocks 0..127 = decoder LSTM (prio 2, t-major hsd + prog);
// blocks 128..4223 = logits GEMM (prio 0), per-XCD n-partition; each m-tile
// is a 4-t-chunk gated on prog >= 4*mt+4. REMAP NT store to out[b*64+t].
__global__ __launch_bounds__(512, 1) void dec_fused(
    const u16* __restrict__ whhD, const float* __restrict__ XpD,
    u16* __restrict__ hbuf, u16* __restrict__ hsd, u32* arrive, u32* prog,
    const u16* __restrict__ wout, float* __restrict__ out,
    const float* __restrict__ b_out) {
  __shared__ __align__(16) char smem[49152];
  if (blockIdx.x < 128) {
    lstm_body(smem, whhD, XpD, hbuf, hsd, nullptr, arrive, prog, blockIdx.x);
    return;
  }
  // ---- logits GEMM part (priority 0)
  u16 (*lA)[256 * 32] = (u16(*)[256 * 32])smem;
  u16 (*lB)[128 * 32] = (u16(*)[128 * 32])(smem + 32768);
  const int tid = threadIdx.x;
  const int lane = tid & 63;
  const int wid = tid >> 6;

  const int i = blockIdx.x - 128;  // 0..4095
  const int x = i & 7;             // XCD id
  const int k = i >> 3;
  const int mg = k >> 6;
  const int r  = k & 63;
  const int kn = r >> 1;
  const int mi = r & 1;
  const int tn = kn * 8 + x;
  if (tn >= 250) return;           // dummy (whole WG exits)
  const int mt = mg * 2 + mi;      // m-tile = t-chunk [mt*4, mt*4+4)
  const int tile_m = mt * 256;
  const int tile_n = tn * 128;
  const int wm = wid >> 1, wn = wid & 1;
  const int N = 32000, K = 1024;

  // ---- wait until decoder steps 0..mt*4+3 are complete in all clusters
  {
    u32 need = (u32)(mt * 4 + 4);
    if (tid < 4) {
      int guard = 0;
      while (__hip_atomic_load(&prog[tid], __ATOMIC_RELAXED,
                               __HIP_MEMORY_SCOPE_AGENT) < need) {
        __builtin_amdgcn_s_sleep(8);
        if (++guard > (1 << 22)) break;   // safety valve
      }
    }
    __syncthreads();
  }

  const int ldr = lane >> 2;
  const int lko = (lane & 3) * 8;
  const int l15 = lane & 15;
  const int g4 = lane >> 4;

  const size_t aBase = (size_t)tile_m * K;
  const size_t bBase = (size_t)tile_n * K;

  f32x4 acc[4][4];
#pragma unroll
  for (int i2 = 0; i2 < 4; ++i2)
#pragma unroll
    for (int j2 = 0; j2 < 4; ++j2) acc[i2][j2] = (f32x4)0.f;

  auto stg = [&](int buf, int k0) {
#pragma unroll
    for (int q = 0; q < 2; ++q) {
      int chk = wid * 2 + q;
      int row = chk * 16 + ldr;
      GLD16(hsd + aBase + (size_t)row * K + k0 + lko, &lA[buf][chk * 512]);
    }
    int row = wid * 16 + ldr;
    GLD16(wout + bBase + (size_t)row * K + k0 + lko, &lB[buf][wid * 512]);
  };

  stg(0, 0);
  __syncthreads();

  const int NIT = K >> 5;
  for (int it = 0; it < NIT; ++it) {
    const int cur = it & 1;
    if (it + 1 < NIT) stg(cur ^ 1, (it + 1) * 32);
    short8 af[4], bf[4];
#pragma unroll
    for (int i2 = 0; i2 < 4; ++i2)
      af[i2] = *(const short8*)&lA[cur][(wm * 64 + i2 * 16 + l15) * 32 + g4 * 8];
#pragma unroll
    for (int j2 = 0; j2 < 4; ++j2)
      bf[j2] = *(const short8*)&lB[cur][(wn * 64 + j2 * 16 + l15) * 32 + g4 * 8];
#pragma unroll
    for (int i2 = 0; i2 < 4; ++i2)
#pragma unroll
      for (int j2 = 0; j2 < 4; ++j2)
        acc[i2][j2] = __builtin_amdgcn_mfma_f32_16x16x32_bf16(af[i2], bf[j2], acc[i2][j2], 0, 0, 0);
    __syncthreads();
  }

#pragma unroll
  for (int i2 = 0; i2 < 4; ++i2) {
    int row0 = tile_m + wm * 64 + i2 * 16 + (g4 << 2);
#pragma unroll
    for (int j2 = 0; j2 < 4; ++j2) {
      int col = tile_n + wn * 64 + j2 * 16 + l15;
      float bv = b_out[col];
#pragma unroll
      for (int e = 0; e < 4; ++e) {
        int rr = row0 + e;                       // t-major row = t*64+b
        size_t o = (size_t)((rr & 63) * 64 + (rr >> 6)) * (size_t)N + col;
        __builtin_nontemporal_store(acc[i2][j2][e] + bv, &out[o]);
      }
    }
  }
}

// ---------------------------------------------------------------------------
// mean/logvar/latent + hd0 = [latent|cond_e] @ W_st^T + b_st -> bf16 h0.
__global__ __launch_bounds__(256) void latent_hd0_kernel(
    const float* hT, const float* Wm, const float* bm,
    const float* Wl, const float* bl, const float* Wst, const float* bst,
    const float* eps, const float* ce, u16* hb0) {
  __shared__ float red[64][4];
  __shared__ float ml[64];
  __shared__ float lat[40];
  int b = blockIdx.x;
  int tid = threadIdx.x;
  int o = tid >> 2, p = tid & 3;
  const float* w = (o < 32) ? (Wm + (size_t)o * 1024) : (Wl + (size_t)(o - 32) * 1024);
  const float* h = hT + (size_t)b * 1024;
  float s = 0.f;
  for (int k = p * 256; k < p * 256 + 256; ++k) s += h[k] * w[k];
  red[o][p] = s;
  __syncthreads();
  if (tid < 64) {
    float v = red[tid][0] + red[tid][1] + red[tid][2] + red[tid][3];
    v += (tid < 32) ? bm[tid] : bl[tid - 32];
    ml[tid] = v;
  }
  __syncthreads();
  if (tid < 32) lat[tid] = eps[b * 32 + tid] * __expf(0.5f * ml[32 + tid]) + ml[tid];
  if (tid >= 32 && tid < 40) lat[tid] = ce[b * 8 + (tid - 32)];
  __syncthreads();
  for (int hc = tid; hc < 1024; hc += 256) {
    float s2 = bst[hc];
    const float* wr = Wst + (size_t)hc * 40;
#pragma unroll
    for (int j = 0; j < 40; ++j) s2 += lat[j] * wr[j];
    hb0[b * 1024 + hc] = f2bf(s2);
  }
}

// ---------------------------------------------------------------------------
extern "C" void kernel_launch(void* const* d_in, const int* in_sizes, int n_in,
                              void* d_out, int out_size, void* d_ws, size_t ws_size,
                              hipStream_t stream) {
  const int*   input_word = (const int*)d_in[0];
  const int*   cond       = (const int*)d_in[1];
  const float* emb_N      = (const float*)d_in[2];
  const float* Wih_N      = (const float*)d_in[3];
  const float* Whh_N      = (const float*)d_in[4];
  const float* bih_N      = (const float*)d_in[5];
  const float* bhh_N      = (const float*)d_in[6];
  const float* emb_D      = (const float*)d_in[7];
  const float* Wih_D      = (const float*)d_in[8];
  const float* Whh_D      = (const float*)d_in[9];
  const float* bih_D      = (const float*)d_in[10];
  const float* bhh_D      = (const float*)d_in[11];
  const float* emb_cond   = (const float*)d_in[12];
  const float* W_mean     = (const float*)d_in[13];
  const float* b_mean     = (const float*)d_in[14];
  const float* W_logvar   = (const float*)d_in[15];
  const float* b_logvar   = (const float*)d_in[16];
  const float* W_st       = (const float*)d_in[17];
  const float* b_st       = (const float*)d_in[18];
  const float* W_out      = (const float*)d_in[19];
  const float* b_out      = (const float*)d_in[20];
  const float* eps        = (const float*)d_in[21];
  float* out = (float*)d_out;

  char* ws = (char*)d_ws;
  size_t off = 0;
  auto alloc = [&](size_t b) { size_t p = off; off += (b + 255) & ~(size_t)255; return p; };
  u16*   wihN = (u16*)(ws + alloc(4096ull * 1024 * 2));
  u16*   whhN = (u16*)(ws + alloc(4096ull * 1024 * 2));
  u16*   wihD = (u16*)(ws + alloc(4096ull * 1024 * 2));
  u16*   whhD = (u16*)(ws + alloc(4096ull * 1024 * 2));
  u16*   wout = (u16*)(ws + alloc(32000ull * 1024 * 2));
  u16*   Xe   = (u16*)(ws + alloc(4096ull * 1024 * 2));
  u16*   Xd   = (u16*)(ws + alloc(4096ull * 1024 * 2));
  float* Xp   = (float*)(ws + alloc(4096ull * 4096 * 4));   // enc (and dec fallback)
  u16*   hsd  = (u16*)(ws + alloc(4096ull * 1024 * 2));     // T-MAJOR [t*64+b][1024]
  u16*   hb   = (u16*)(ws + alloc(2ull * 64 * 1024 * 2));   // bf16 h dbuf
  float* hf   = (float*)(ws + alloc(64ull * 1024 * 4));     // fp32 h_T (encoder)
  float* biasN = (float*)(ws + alloc(4096 * 4));
  float* biasD = (float*)(ws + alloc(4096 * 4));
  float* ce    = (float*)(ws + alloc(64 * 8 * 4));
  u32*   bar   = (u32*)(ws + alloc(4096));
  // bar: enc arrive [0..127], dec arrive [256..383], dec prog [512..515]
  size_t base_off = off;
  float* XpD2 = (float*)(ws + alloc(4096ull * 4096 * 4));   // dec Xp (fused path)
  if (base_off > ws_size) return;
  const bool fused = (off <= ws_size);
  float* XpD = fused ? XpD2 : Xp;

  conv4<<<16384, 256, 0, stream>>>(Wih_N, wihN, Whh_N, whhN,
                                   Wih_D, wihD, Whh_D, whhD);
  prep_small<<<22, 256, 0, stream>>>(cond, emb_cond, bih_N, bhh_N, bih_D, bhh_D,
                                     ce, biasN, biasD, bar);
  gather_kernel<<<4096, 256, 0, stream>>>(emb_N, input_word, Xe, 0);
  gather_kernel<<<4096, 256, 0, stream>>>(emb_D, input_word, Xd, 1);
  init_enc<<<256, 256, 0, stream>>>(ce, hb);

  // encoder Xp
  gemm_bt0<<<512, 512, 0, stream>>>(Xe, wihN, Xp, biasN, 4096, 1024);
  if (fused) {
    // encoder LSTM + decoder-Xp GEMM + W_out conversion, one launch
    enc_fused<<<1152, 512, 0, stream>>>(whhN, Xp, hb, hf, bar + 0,
                                        Xd, wihD, XpD, biasD, W_out, wout);
  } else {
    conv_wout<<<32000, 256, 0, stream>>>(W_out, wout);
    lstm_cluster<<<128, 512, 0, stream>>>(whhN, Xp, hb, hf, bar + 0);
  }
  // latent + decoder h0
  latent_hd0_kernel<<<64, 256, 0, stream>>>(hf, W_mean, b_mean, W_logvar, b_logvar,
                                            W_st, b_st, eps, ce, hb);
  if (!fused)
    gemm_bt0<<<512, 512, 0, stream>>>(Xd, wihD, XpD, biasD, 4096, 1024);
  // decoder LSTM + logits GEMM fused (producer-consumer on hsd via prog[])
  dec_fused<<<4224, 512, 0, stream>>>(whhD, XpD, hb, hsd, bar + 256, bar + 512,
                                      wout, out, b_out);
}